// Round 5
// baseline (217.470 us; speedup 1.0000x reference)
//
#include <hip/hip_runtime.h>
#include <hip/hip_bf16.h>
#include <math.h>

// ---------------- helpers ----------------

__device__ __forceinline__ float wave_max64(float v) {
#pragma unroll
  for (int o = 32; o > 0; o >>= 1) v = fmaxf(v, __shfl_xor(v, o));
  return v;
}
__device__ __forceinline__ float wave_sum64(float v) {
#pragma unroll
  for (int o = 32; o > 0; o >>= 1) v += __shfl_xor(v, o);
  return v;
}
__device__ __forceinline__ float leaky02(float v) { return v > 0.0f ? v : 0.2f * v; }

// bf16 pack/unpack (RNE)
__device__ __forceinline__ unsigned short f2bf(float f) {
  unsigned u = __float_as_uint(f);
  u += 0x7FFF + ((u >> 16) & 1);
  return (unsigned short)(u >> 16);
}
__device__ __forceinline__ float2 bfp(unsigned v) {
  float2 r;
  r.x = __uint_as_float(v << 16);
  r.y = __uint_as_float(v & 0xFFFF0000u);
  return r;
}

// ---------------- CSR build: 2-level bucket sort ----------------

#define BSHIFT 9
#define BDSTS 512

__global__ __launch_bounds__(256) void bucket_hist_kernel(
    const int* __restrict__ ei, int* __restrict__ bcount, int E, int NBUCK) {
  __shared__ int h[128];
  if (threadIdx.x < 128) h[threadIdx.x] = 0;
  __syncthreads();
  for (int e = blockIdx.x * blockDim.x + threadIdx.x; e < E; e += gridDim.x * blockDim.x)
    atomicAdd(&h[ei[E + e] >> BSHIFT], 1);
  __syncthreads();
  if (threadIdx.x < NBUCK && h[threadIdx.x]) atomicAdd(&bcount[threadIdx.x], h[threadIdx.x]);
}

__global__ __launch_bounds__(128) void bucket_scan_kernel(
    const int* __restrict__ bcount, int* __restrict__ bstart, int* __restrict__ bcursor,
    int* __restrict__ row_start, int NBUCK, int E, int N) {
  __shared__ int lds[128];
  int t = threadIdx.x;
  int v = (t < NBUCK) ? bcount[t] : 0;
  lds[t] = v;
  __syncthreads();
#pragma unroll
  for (int off = 1; off < 128; off <<= 1) {
    int tmp = (t >= off) ? lds[t - off] : 0;
    __syncthreads();
    lds[t] += tmp;
    __syncthreads();
  }
  if (t < NBUCK) {
    int excl = lds[t] - v;
    bstart[t] = excl;
    bcursor[t] = excl;
  }
  if (t == 0) { bstart[NBUCK] = E; row_start[N] = E; }
}

#define CHUNK 4096
__global__ __launch_bounds__(256) void pair_scatter_kernel(
    const int* __restrict__ ei, int* __restrict__ bcursor, int2* __restrict__ pairs, int E) {
  __shared__ int h[128], base[128], cur[128];
  if (threadIdx.x < 128) { h[threadIdx.x] = 0; cur[threadIdx.x] = 0; }
  __syncthreads();
  int c0 = blockIdx.x * CHUNK;
  int c1 = min(c0 + CHUNK, E);
  for (int e = c0 + (int)threadIdx.x; e < c1; e += 256)
    atomicAdd(&h[ei[E + e] >> BSHIFT], 1);
  __syncthreads();
  if (threadIdx.x < 128 && h[threadIdx.x])
    base[threadIdx.x] = atomicAdd(&bcursor[threadIdx.x], h[threadIdx.x]);
  __syncthreads();
  for (int e = c0 + (int)threadIdx.x; e < c1; e += 256) {
    int dst = ei[E + e];
    int src = ei[e];
    int b = dst >> BSHIFT;
    int r = atomicAdd(&cur[b], 1);
    pairs[base[b] + r] = make_int2(src, dst);
  }
}

__global__ __launch_bounds__(512) void fine_kernel(
    const int2* __restrict__ pairs, const int* __restrict__ bstart,
    int* __restrict__ row_start, int* __restrict__ esrc, int N) {
  __shared__ int h[BDSTS], sc[BDSTS], cur[BDSTS];
  int t = threadIdx.x;
  int b = blockIdx.x;
  int d0 = b << BSHIFT;
  int d1 = min(d0 + BDSTS, N);
  int beg = bstart[b], end = bstart[b + 1];
  h[t] = 0;
  __syncthreads();
  for (int i = beg + t; i < end; i += 512) atomicAdd(&h[pairs[i].y - d0], 1);
  __syncthreads();
  int v = h[t];
  sc[t] = v;
  __syncthreads();
#pragma unroll
  for (int off = 1; off < BDSTS; off <<= 1) {
    int tmp = (t >= off) ? sc[t - off] : 0;
    __syncthreads();
    sc[t] += tmp;
    __syncthreads();
  }
  int excl = sc[t] - v;
  if (d0 + t < d1) row_start[d0 + t] = beg + excl;
  cur[t] = excl;
  __syncthreads();
  for (int i = beg + t; i < end; i += 512) {
    int2 p = pairs[i];
    int r = atomicAdd(&cur[p.y - d0], 1);
    esrc[beg + r] = p.x;
  }
}

// ---------------- GEMM: 8x8 register blocking, LDS tiled ----------------
// 128 threads (2 waves); tile 64 rows x 128 cols, K chunks of 32.
// tx = tid&15: col quads {tx*4, 64+tx*4}; ty = tid>>4: rows ty*8..+7.
// Per k: 2 b128 A + 2 b128 B -> 64 FMAs (conflict-free bank patterns).

#define XIDX(k, m) ((k) * 64 + ((m) ^ ((((k) >> 2) & 7) << 3)))

__global__ __launch_bounds__(128) void gemm1_kernel(
    const float* __restrict__ X, const float* __restrict__ W,
    const float* __restrict__ a_src, const float* __restrict__ a_dst,
    unsigned short* __restrict__ Hb, float* __restrict__ asrc, float* __restrict__ adst, int N) {
  __shared__ float Xs[32 * 64];
  __shared__ float Ws[32 * 128];
  const int tid = threadIdx.x;
  const int tx = tid & 15, ty = tid >> 4;
  const int rowBase = blockIdx.x * 64;
  const int r0 = ty * 8;
  const int cA = tx * 4, cB = 64 + tx * 4;

  float acc[8][8];
#pragma unroll
  for (int r = 0; r < 8; ++r)
#pragma unroll
    for (int c = 0; c < 8; ++c) acc[r][c] = 0.f;

  for (int kc = 0; kc < 4; ++kc) {
    const int k0 = kc * 32;
    // stage X chunk transposed+swizzled: 512 float4, 4 per thread
#pragma unroll
    for (int j = 0; j < 4; ++j) {
      int i = tid + j * 128;
      int m = i >> 3, kq = i & 7;
      int row = rowBase + m;
      float4 v = make_float4(0.f, 0.f, 0.f, 0.f);
      if (row < N) v = *(const float4*)(X + (size_t)row * 128 + k0 + kq * 4);
      Xs[XIDX(kq * 4 + 0, m)] = v.x;
      Xs[XIDX(kq * 4 + 1, m)] = v.y;
      Xs[XIDX(kq * 4 + 2, m)] = v.z;
      Xs[XIDX(kq * 4 + 3, m)] = v.w;
    }
    // stage W chunk: 1024 float4, 8 per thread
#pragma unroll
    for (int j = 0; j < 8; ++j) {
      int i = tid + j * 128;
      int k = i >> 5, c = (i & 31) * 4;
      *(float4*)&Ws[k * 128 + c] = *(const float4*)(W + (size_t)(k0 + k) * 128 + c);
    }
    __syncthreads();
#pragma unroll 8
    for (int k = 0; k < 32; ++k) {
      const int swz = ((k >> 2) & 7) << 3;
      float4 a0 = *(const float4*)&Xs[k * 64 + (r0 ^ swz)];
      float4 a1 = *(const float4*)&Xs[k * 64 + ((r0 + 4) ^ swz)];
      float4 b0 = *(const float4*)&Ws[k * 128 + cA];
      float4 b1 = *(const float4*)&Ws[k * 128 + cB];
      float av[8] = {a0.x, a0.y, a0.z, a0.w, a1.x, a1.y, a1.z, a1.w};
      float bv[8] = {b0.x, b0.y, b0.z, b0.w, b1.x, b1.y, b1.z, b1.w};
#pragma unroll
      for (int r = 0; r < 8; ++r)
#pragma unroll
        for (int c = 0; c < 8; ++c) acc[r][c] = fmaf(av[r], bv[c], acc[r][c]);
    }
    __syncthreads();
  }

  float asA[4], asB[4], dsA[4], dsB[4];
#pragma unroll
  for (int c = 0; c < 4; ++c) {
    asA[c] = a_src[cA + c]; asB[c] = a_src[cB + c];
    dsA[c] = a_dst[cA + c]; dsB[c] = a_dst[cB + c];
  }
#pragma unroll
  for (int r = 0; r < 8; ++r) {
    int row = rowBase + r0 + r;
    if (row >= N) break;
    uint2 pA, pB;
    pA.x = (unsigned)f2bf(acc[r][0]) | ((unsigned)f2bf(acc[r][1]) << 16);
    pA.y = (unsigned)f2bf(acc[r][2]) | ((unsigned)f2bf(acc[r][3]) << 16);
    pB.x = (unsigned)f2bf(acc[r][4]) | ((unsigned)f2bf(acc[r][5]) << 16);
    pB.y = (unsigned)f2bf(acc[r][6]) | ((unsigned)f2bf(acc[r][7]) << 16);
    *(uint2*)(Hb + (size_t)row * 128 + cA) = pA;
    *(uint2*)(Hb + (size_t)row * 128 + cB) = pB;
    float ps = 0.f, pd = 0.f;
#pragma unroll
    for (int c = 0; c < 4; ++c) {
      ps = fmaf(acc[r][c], asA[c], fmaf(acc[r][c + 4], asB[c], ps));
      pd = fmaf(acc[r][c], dsA[c], fmaf(acc[r][c + 4], dsB[c], pd));
    }
#pragma unroll
    for (int o = 8; o > 0; o >>= 1) { ps += __shfl_xor(ps, o); pd += __shfl_xor(pd, o); }
    if (tx == 0) { asrc[row] = ps; adst[row] = pd; }
  }
}

__global__ __launch_bounds__(128) void gemm2_kernel(
    const float* __restrict__ X,
    const float* __restrict__ W_mu, const float* __restrict__ W_ls,
    const float* __restrict__ a_src_mu, const float* __restrict__ a_dst_mu,
    const float* __restrict__ a_src_ls, const float* __restrict__ a_dst_ls,
    unsigned short* __restrict__ Hb,
    float* __restrict__ as2, float* __restrict__ ad2, int N) {
  __shared__ float Xs[32 * 64];
  __shared__ float Ws[32 * 128];
  const int tid = threadIdx.x;
  const int tx = tid & 15, ty = tid >> 4;
  const int rowBase = blockIdx.x * 64;
  const int r0 = ty * 8;
  const int cA = tx * 4, cB = 64 + tx * 4;  // cA: mu cols, cB: ls cols (+64)

  float acc[8][8];
#pragma unroll
  for (int r = 0; r < 8; ++r)
#pragma unroll
    for (int c = 0; c < 8; ++c) acc[r][c] = 0.f;

  for (int kc = 0; kc < 4; ++kc) {
    const int k0 = kc * 32;
#pragma unroll
    for (int j = 0; j < 4; ++j) {
      int i = tid + j * 128;
      int m = i >> 3, kq = i & 7;
      int row = rowBase + m;
      float4 v = make_float4(0.f, 0.f, 0.f, 0.f);
      if (row < N) v = *(const float4*)(X + (size_t)row * 128 + k0 + kq * 4);
      Xs[XIDX(kq * 4 + 0, m)] = v.x;
      Xs[XIDX(kq * 4 + 1, m)] = v.y;
      Xs[XIDX(kq * 4 + 2, m)] = v.z;
      Xs[XIDX(kq * 4 + 3, m)] = v.w;
    }
    // stage [W_mu | W_ls]: each 512 float4, 4 per thread each
#pragma unroll
    for (int j = 0; j < 4; ++j) {
      int i = tid + j * 128;
      int k = i >> 4, c = (i & 15) * 4;
      *(float4*)&Ws[k * 128 + c] = *(const float4*)(W_mu + (size_t)(k0 + k) * 64 + c);
      *(float4*)&Ws[k * 128 + 64 + c] = *(const float4*)(W_ls + (size_t)(k0 + k) * 64 + c);
    }
    __syncthreads();
#pragma unroll 8
    for (int k = 0; k < 32; ++k) {
      const int swz = ((k >> 2) & 7) << 3;
      float4 a0 = *(const float4*)&Xs[k * 64 + (r0 ^ swz)];
      float4 a1 = *(const float4*)&Xs[k * 64 + ((r0 + 4) ^ swz)];
      float4 b0 = *(const float4*)&Ws[k * 128 + cA];
      float4 b1 = *(const float4*)&Ws[k * 128 + cB];
      float av[8] = {a0.x, a0.y, a0.z, a0.w, a1.x, a1.y, a1.z, a1.w};
      float bv[8] = {b0.x, b0.y, b0.z, b0.w, b1.x, b1.y, b1.z, b1.w};
#pragma unroll
      for (int r = 0; r < 8; ++r)
#pragma unroll
        for (int c = 0; c < 8; ++c) acc[r][c] = fmaf(av[r], bv[c], acc[r][c]);
    }
    __syncthreads();
  }

  float asm_[4], adm_[4], asl_[4], adl_[4];
#pragma unroll
  for (int c = 0; c < 4; ++c) {
    asm_[c] = a_src_mu[tx * 4 + c]; adm_[c] = a_dst_mu[tx * 4 + c];
    asl_[c] = a_src_ls[tx * 4 + c]; adl_[c] = a_dst_ls[tx * 4 + c];
  }
#pragma unroll
  for (int r = 0; r < 8; ++r) {
    int row = rowBase + r0 + r;
    if (row >= N) break;
    uint2 pA, pB;
    pA.x = (unsigned)f2bf(acc[r][0]) | ((unsigned)f2bf(acc[r][1]) << 16);
    pA.y = (unsigned)f2bf(acc[r][2]) | ((unsigned)f2bf(acc[r][3]) << 16);
    pB.x = (unsigned)f2bf(acc[r][4]) | ((unsigned)f2bf(acc[r][5]) << 16);
    pB.y = (unsigned)f2bf(acc[r][6]) | ((unsigned)f2bf(acc[r][7]) << 16);
    *(uint2*)(Hb + (size_t)row * 128 + cA) = pA;
    *(uint2*)(Hb + (size_t)row * 128 + cB) = pB;
    float psm = 0.f, pdm = 0.f, psl = 0.f, pdl = 0.f;
#pragma unroll
    for (int c = 0; c < 4; ++c) {
      psm = fmaf(acc[r][c], asm_[c], psm);
      pdm = fmaf(acc[r][c], adm_[c], pdm);
      psl = fmaf(acc[r][c + 4], asl_[c], psl);
      pdl = fmaf(acc[r][c + 4], adl_[c], pdl);
    }
#pragma unroll
    for (int o = 8; o > 0; o >>= 1) {
      psm += __shfl_xor(psm, o); pdm += __shfl_xor(pdm, o);
      psl += __shfl_xor(psl, o); pdl += __shfl_xor(pdl, o);
    }
    if (tx == 0) {
      as2[2 * row] = psm; ad2[2 * row] = pdm;
      as2[2 * row + 1] = psl; ad2[2 * row + 1] = pdl;
    }
  }
}

// ---------------- Aggregation layer 1 (bf16 gather, fp32 math, + bias + ReLU) ----------------

__global__ __launch_bounds__(256) void agg1_kernel(
    const unsigned short* __restrict__ Hb, const float* __restrict__ asrc,
    const float* __restrict__ adst,
    const int* __restrict__ row_start, const int* __restrict__ esrc,
    const float* __restrict__ b, float* __restrict__ hout, int N) {
  int lane = threadIdx.x & 63;
  int d = (int)((blockIdx.x * blockDim.x + threadIdx.x) >> 6);
  if (d >= N) return;
  float ad = adst[d];
  float m = leaky02(asrc[d] + ad);
  float denom = 1.0f;
  float2 acc = bfp(((const unsigned*)(Hb + (size_t)d * 128))[lane]);
  int beg = row_start[d], end = row_start[d + 1];
  for (int base = beg; base < end; base += 64) {
    int nv = end - base;
    if (nv > 64) nv = 64;
    float e = -INFINITY;
    int s = 0;
    if (lane < nv) {
      s = esrc[base + lane];
      e = leaky02(asrc[s] + ad);
    }
    float cm = wave_max64(e);
    if (cm > m) {
      float sc = __expf(m - cm);
      denom *= sc; acc.x *= sc; acc.y *= sc;
      m = cm;
    }
    float w = __expf(e - m);
    denom += wave_sum64(w);
    int j = 0;
    for (; j + 4 <= nv; j += 4) {
      int s0 = __shfl(s, j), s1 = __shfl(s, j + 1), s2 = __shfl(s, j + 2), s3 = __shfl(s, j + 3);
      float w0 = __shfl(w, j), w1 = __shfl(w, j + 1), w2 = __shfl(w, j + 2), w3 = __shfl(w, j + 3);
      unsigned v0 = ((const unsigned*)(Hb + (size_t)s0 * 128))[lane];
      unsigned v1 = ((const unsigned*)(Hb + (size_t)s1 * 128))[lane];
      unsigned v2 = ((const unsigned*)(Hb + (size_t)s2 * 128))[lane];
      unsigned v3 = ((const unsigned*)(Hb + (size_t)s3 * 128))[lane];
      float2 f0 = bfp(v0), f1 = bfp(v1), f2 = bfp(v2), f3 = bfp(v3);
      acc.x = fmaf(w0, f0.x, acc.x); acc.y = fmaf(w0, f0.y, acc.y);
      acc.x = fmaf(w1, f1.x, acc.x); acc.y = fmaf(w1, f1.y, acc.y);
      acc.x = fmaf(w2, f2.x, acc.x); acc.y = fmaf(w2, f2.y, acc.y);
      acc.x = fmaf(w3, f3.x, acc.x); acc.y = fmaf(w3, f3.y, acc.y);
    }
    for (; j < nv; ++j) {
      int sj = __shfl(s, j);
      float wj = __shfl(w, j);
      float2 f = bfp(((const unsigned*)(Hb + (size_t)sj * 128))[lane]);
      acc.x = fmaf(wj, f.x, acc.x);
      acc.y = fmaf(wj, f.y, acc.y);
    }
  }
  float inv = 1.0f / denom;
  float2 bv = ((const float2*)b)[lane];
  float2 o;
  o.x = fmaxf(fmaf(acc.x, inv, bv.x), 0.0f);
  o.y = fmaxf(fmaf(acc.y, inv, bv.y), 0.0f);
  ((float2*)(hout + (size_t)d * 128))[lane] = o;
}

// ---------------- Aggregation layers 2+3 fused (mu lanes 0-31, ls lanes 32-63) ----------------

__global__ __launch_bounds__(256) void agg2_kernel(
    const unsigned short* __restrict__ Hb,
    const float2* __restrict__ as2, const float2* __restrict__ ad2,
    const int* __restrict__ row_start, const int* __restrict__ esrc,
    const float* __restrict__ b_mu, const float* __restrict__ b_ls,
    float* __restrict__ out_mu, float* __restrict__ out_ls, int N) {
  int lane = threadIdx.x & 63;
  int d = (int)((blockIdx.x * blockDim.x + threadIdx.x) >> 6);
  if (d >= N) return;
  bool isMu = lane < 32;
  float2 a2d = ad2[d];
  float2 a2s_self = as2[d];
  float m_mu = leaky02(a2s_self.x + a2d.x);
  float m_ls = leaky02(a2s_self.y + a2d.y);
  float den_mu = 1.0f, den_ls = 1.0f;
  float2 acc = bfp(((const unsigned*)(Hb + (size_t)d * 128))[lane]);
  int beg = row_start[d], end = row_start[d + 1];
  for (int base = beg; base < end; base += 64) {
    int nv = end - base;
    if (nv > 64) nv = 64;
    float e_mu = -INFINITY, e_ls = -INFINITY;
    int s = 0;
    if (lane < nv) {
      s = esrc[base + lane];
      float2 av = as2[s];
      e_mu = leaky02(av.x + a2d.x);
      e_ls = leaky02(av.y + a2d.y);
    }
    float cm_mu = wave_max64(e_mu);
    float cm_ls = wave_max64(e_ls);
    float sc_mu = 1.0f, sc_ls = 1.0f;
    if (cm_mu > m_mu) { sc_mu = __expf(m_mu - cm_mu); den_mu *= sc_mu; m_mu = cm_mu; }
    if (cm_ls > m_ls) { sc_ls = __expf(m_ls - cm_ls); den_ls *= sc_ls; m_ls = cm_ls; }
    float sc = isMu ? sc_mu : sc_ls;
    acc.x *= sc; acc.y *= sc;
    float w_mu = __expf(e_mu - m_mu);
    float w_ls = __expf(e_ls - m_ls);
    den_mu += wave_sum64(w_mu);
    den_ls += wave_sum64(w_ls);
    int j = 0;
    for (; j + 4 <= nv; j += 4) {
      int s0 = __shfl(s, j), s1 = __shfl(s, j + 1), s2 = __shfl(s, j + 2), s3 = __shfl(s, j + 3);
      float wm0 = __shfl(w_mu, j), wm1 = __shfl(w_mu, j + 1), wm2 = __shfl(w_mu, j + 2), wm3 = __shfl(w_mu, j + 3);
      float wl0 = __shfl(w_ls, j), wl1 = __shfl(w_ls, j + 1), wl2 = __shfl(w_ls, j + 2), wl3 = __shfl(w_ls, j + 3);
      float w0 = isMu ? wm0 : wl0, w1 = isMu ? wm1 : wl1, w2 = isMu ? wm2 : wl2, w3 = isMu ? wm3 : wl3;
      unsigned v0 = ((const unsigned*)(Hb + (size_t)s0 * 128))[lane];
      unsigned v1 = ((const unsigned*)(Hb + (size_t)s1 * 128))[lane];
      unsigned v2 = ((const unsigned*)(Hb + (size_t)s2 * 128))[lane];
      unsigned v3 = ((const unsigned*)(Hb + (size_t)s3 * 128))[lane];
      float2 f0 = bfp(v0), f1 = bfp(v1), f2 = bfp(v2), f3 = bfp(v3);
      acc.x = fmaf(w0, f0.x, acc.x); acc.y = fmaf(w0, f0.y, acc.y);
      acc.x = fmaf(w1, f1.x, acc.x); acc.y = fmaf(w1, f1.y, acc.y);
      acc.x = fmaf(w2, f2.x, acc.x); acc.y = fmaf(w2, f2.y, acc.y);
      acc.x = fmaf(w3, f3.x, acc.x); acc.y = fmaf(w3, f3.y, acc.y);
    }
    for (; j < nv; ++j) {
      float wj_mu = __shfl(w_mu, j);
      float wj_ls = __shfl(w_ls, j);
      float wj = isMu ? wj_mu : wj_ls;
      int sj = __shfl(s, j);
      float2 f = bfp(((const unsigned*)(Hb + (size_t)sj * 128))[lane]);
      acc.x = fmaf(wj, f.x, acc.x);
      acc.y = fmaf(wj, f.y, acc.y);
    }
  }
  float inv = isMu ? (1.0f / den_mu) : (1.0f / den_ls);
  float2 bv = isMu ? ((const float2*)b_mu)[lane] : ((const float2*)b_ls)[lane - 32];
  float2 o;
  o.x = fmaf(acc.x, inv, bv.x);
  o.y = fmaf(acc.y, inv, bv.y);
  if (isMu) ((float2*)(out_mu + (size_t)d * 64))[lane] = o;
  else      ((float2*)(out_ls + (size_t)d * 64))[lane - 32] = o;
}

// ---------------- launch ----------------

extern "C" void kernel_launch(void* const* d_in, const int* in_sizes, int n_in,
                              void* d_out, int out_size, void* d_ws, size_t ws_size,
                              hipStream_t stream) {
  const float* x = (const float*)d_in[0];
  const int* ei = (const int*)d_in[1];
  const float* W1 = (const float*)d_in[2];
  const float* a_src1 = (const float*)d_in[3];
  const float* a_dst1 = (const float*)d_in[4];
  const float* b1 = (const float*)d_in[5];
  const float* W_mu = (const float*)d_in[6];
  const float* a_src_mu = (const float*)d_in[7];
  const float* a_dst_mu = (const float*)d_in[8];
  const float* b_mu = (const float*)d_in[9];
  const float* W_ls = (const float*)d_in[10];
  const float* a_src_ls = (const float*)d_in[11];
  const float* a_dst_ls = (const float*)d_in[12];
  const float* b_ls = (const float*)d_in[13];

  const int N = in_sizes[0] / 128;  // 50000
  const int E = in_sizes[1] / 2;    // 800000
  const int NBUCK = (N + BDSTS - 1) >> BSHIFT;  // 98 (<=128)

  uint8_t* p = (uint8_t*)d_ws;
  auto carve = [&](size_t bytes) -> void* {
    void* q = (void*)p;
    p += (bytes + 255) & ~(size_t)255;
    return q;
  };
  int* bcount = (int*)carve((size_t)(NBUCK + 1) * 4);
  int* bstart = (int*)carve((size_t)(NBUCK + 1) * 4);
  int* bcursor = (int*)carve((size_t)NBUCK * 4);
  int* row_start = (int*)carve((size_t)(N + 1) * 4);
  int* esrc = (int*)carve((size_t)E * 4);
  int2* pairs = (int2*)carve((size_t)E * 8);
  unsigned short* Hb1 = (unsigned short*)carve((size_t)N * 128 * 2);  // bf16; reused as Hb2
  float* h1 = (float*)carve((size_t)N * 128 * 4);
  float* as1 = (float*)carve((size_t)N * 4);
  float* ad1 = (float*)carve((size_t)N * 4);
  float* as2 = (float*)carve((size_t)N * 8);
  float* ad2 = (float*)carve((size_t)N * 8);

  unsigned short* Hb2 = Hb1;

  hipMemsetAsync(bcount, 0, (size_t)(NBUCK + 1) * 4, stream);
  bucket_hist_kernel<<<(E + 2047) / 2048, 256, 0, stream>>>(ei, bcount, E, NBUCK);
  bucket_scan_kernel<<<1, 128, 0, stream>>>(bcount, bstart, bcursor, row_start, NBUCK, E, N);
  pair_scatter_kernel<<<(E + CHUNK - 1) / CHUNK, 256, 0, stream>>>(ei, bcursor, pairs, E);
  fine_kernel<<<NBUCK, 512, 0, stream>>>(pairs, bstart, row_start, esrc, N);

  gemm1_kernel<<<(N + 63) / 64, 128, 0, stream>>>(x, W1, a_src1, a_dst1, Hb1, as1, ad1, N);
  agg1_kernel<<<(N + 3) / 4, 256, 0, stream>>>(Hb1, as1, ad1, row_start, esrc, b1, h1, N);
  gemm2_kernel<<<(N + 63) / 64, 128, 0, stream>>>(h1, W_mu, W_ls, a_src_mu, a_dst_mu,
                                                  a_src_ls, a_dst_ls, Hb2, as2, ad2, N);
  float* out_mu = (float*)d_out;
  float* out_ls = out_mu + (size_t)N * 64;
  agg2_kernel<<<(N + 3) / 4, 256, 0, stream>>>(Hb2, (const float2*)as2, (const float2*)ad2,
                                               row_start, esrc, b_mu, b_ls, out_mu, out_ls, N);
}

// Round 6
// 183.946 us; speedup vs baseline: 1.1823x; 1.1823x over previous
//
#include <hip/hip_runtime.h>
#include <hip/hip_bf16.h>
#include <math.h>

typedef __attribute__((ext_vector_type(8))) _Float16 half8;
typedef __attribute__((ext_vector_type(4))) float f32x4;

// ---------------- helpers ----------------

__device__ __forceinline__ float wave_max64(float v) {
#pragma unroll
  for (int o = 32; o > 0; o >>= 1) v = fmaxf(v, __shfl_xor(v, o));
  return v;
}
__device__ __forceinline__ float wave_sum64(float v) {
#pragma unroll
  for (int o = 32; o > 0; o >>= 1) v += __shfl_xor(v, o);
  return v;
}
__device__ __forceinline__ float leaky02(float v) { return v > 0.0f ? v : 0.2f * v; }

// bf16 pack/unpack (RNE)
__device__ __forceinline__ unsigned short f2bf(float f) {
  unsigned u = __float_as_uint(f);
  u += 0x7FFF + ((u >> 16) & 1);
  return (unsigned short)(u >> 16);
}
__device__ __forceinline__ float2 bfp(unsigned v) {
  float2 r;
  r.x = __uint_as_float(v << 16);
  r.y = __uint_as_float(v & 0xFFFF0000u);
  return r;
}

// ---------------- CSR build: 2-level bucket sort ----------------

#define BSHIFT 9
#define BDSTS 512

__global__ __launch_bounds__(256) void bucket_hist_kernel(
    const int* __restrict__ ei, int* __restrict__ bcount, int E, int NBUCK) {
  __shared__ int h[128];
  if (threadIdx.x < 128) h[threadIdx.x] = 0;
  __syncthreads();
  for (int e = blockIdx.x * blockDim.x + threadIdx.x; e < E; e += gridDim.x * blockDim.x)
    atomicAdd(&h[ei[E + e] >> BSHIFT], 1);
  __syncthreads();
  if (threadIdx.x < NBUCK && h[threadIdx.x]) atomicAdd(&bcount[threadIdx.x], h[threadIdx.x]);
}

__global__ __launch_bounds__(128) void bucket_scan_kernel(
    const int* __restrict__ bcount, int* __restrict__ bstart, int* __restrict__ bcursor,
    int* __restrict__ row_start, int NBUCK, int E, int N) {
  __shared__ int lds[128];
  int t = threadIdx.x;
  int v = (t < NBUCK) ? bcount[t] : 0;
  lds[t] = v;
  __syncthreads();
#pragma unroll
  for (int off = 1; off < 128; off <<= 1) {
    int tmp = (t >= off) ? lds[t - off] : 0;
    __syncthreads();
    lds[t] += tmp;
    __syncthreads();
  }
  if (t < NBUCK) {
    int excl = lds[t] - v;
    bstart[t] = excl;
    bcursor[t] = excl;
  }
  if (t == 0) { bstart[NBUCK] = E; row_start[N] = E; }
}

#define CHUNK 4096
__global__ __launch_bounds__(256) void pair_scatter_kernel(
    const int* __restrict__ ei, int* __restrict__ bcursor, int2* __restrict__ pairs, int E) {
  __shared__ int h[128], base[128], cur[128];
  if (threadIdx.x < 128) { h[threadIdx.x] = 0; cur[threadIdx.x] = 0; }
  __syncthreads();
  int c0 = blockIdx.x * CHUNK;
  int c1 = min(c0 + CHUNK, E);
  for (int e = c0 + (int)threadIdx.x; e < c1; e += 256)
    atomicAdd(&h[ei[E + e] >> BSHIFT], 1);
  __syncthreads();
  if (threadIdx.x < 128 && h[threadIdx.x])
    base[threadIdx.x] = atomicAdd(&bcursor[threadIdx.x], h[threadIdx.x]);
  __syncthreads();
  for (int e = c0 + (int)threadIdx.x; e < c1; e += 256) {
    int dst = ei[E + e];
    int src = ei[e];
    int b = dst >> BSHIFT;
    int r = atomicAdd(&cur[b], 1);
    pairs[base[b] + r] = make_int2(src, dst);
  }
}

__global__ __launch_bounds__(512) void fine_kernel(
    const int2* __restrict__ pairs, const int* __restrict__ bstart,
    int* __restrict__ row_start, int* __restrict__ esrc, int N) {
  __shared__ int h[BDSTS], sc[BDSTS], cur[BDSTS];
  int t = threadIdx.x;
  int b = blockIdx.x;
  int d0 = b << BSHIFT;
  int d1 = min(d0 + BDSTS, N);
  int beg = bstart[b], end = bstart[b + 1];
  h[t] = 0;
  __syncthreads();
  for (int i = beg + t; i < end; i += 512) atomicAdd(&h[pairs[i].y - d0], 1);
  __syncthreads();
  int v = h[t];
  sc[t] = v;
  __syncthreads();
#pragma unroll
  for (int off = 1; off < BDSTS; off <<= 1) {
    int tmp = (t >= off) ? sc[t - off] : 0;
    __syncthreads();
    sc[t] += tmp;
    __syncthreads();
  }
  int excl = sc[t] - v;
  if (d0 + t < d1) row_start[d0 + t] = beg + excl;
  cur[t] = excl;
  __syncthreads();
  for (int i = beg + t; i < end; i += 512) {
    int2 p = pairs[i];
    int r = atomicAdd(&cur[p.y - d0], 1);
    esrc[beg + r] = p.x;
  }
}

// ---------------- W prep: fp16 transposed weights ----------------
// Wt1[c][k] = W1[k][c];  Wt2[c][k] = c<64 ? W_mu[k][c] : W_ls[k][c-64]

__global__ __launch_bounds__(256) void prep_w_kernel(
    const float* __restrict__ W1, const float* __restrict__ Wmu, const float* __restrict__ Wls,
    _Float16* __restrict__ Wt1, _Float16* __restrict__ Wt2) {
  int idx = blockIdx.x * 256 + threadIdx.x;  // 16384 total
  int c = idx >> 7, k = idx & 127;
  Wt1[idx] = (_Float16)W1[k * 128 + c];
  float w2 = (c < 64) ? Wmu[k * 64 + c] : Wls[k * 64 + (c - 64)];
  Wt2[idx] = (_Float16)w2;
}

// ---------------- GEMM via MFMA (fp16 in, fp32 acc), no LDS, no barriers ----------------
// 256 thr = 4 waves; wave owns 16 rows x 128 cols = 8 tiles of 16x16, K=128 in 4 steps of 32.
// A: row = lane&15, k = (lane>>4)*8 + j (8 consecutive k).
// B: col = lane&15, k = (lane>>4)*8 + j  (from Wt[col][k], contiguous 16B).
// C/D: col = lane&15, row = (lane>>4)*4 + reg.

__global__ __launch_bounds__(256) void gemm1_mfma(
    const float* __restrict__ X, const _Float16* __restrict__ Wt,
    const float* __restrict__ a_src, const float* __restrict__ a_dst,
    unsigned short* __restrict__ Hb, float* __restrict__ asrc, float* __restrict__ adst, int N) {
  const int wid = threadIdx.x >> 6, lane = threadIdx.x & 63;
  const int r16 = (blockIdx.x * 4 + wid) * 16;
  if (r16 >= N) return;
  const int cg = lane & 15;
  const int kq = (lane >> 4) * 8;
  const int rA = r16 + cg;                 // A-row carried by this lane
  const int rowClamp = min(rA, N - 1);

  f32x4 acc[8];
#pragma unroll
  for (int j = 0; j < 8; ++j) acc[j] = (f32x4){0.f, 0.f, 0.f, 0.f};

#pragma unroll
  for (int ks = 0; ks < 4; ++ks) {
    const int k0 = ks * 32;
    const float* xp = X + (size_t)rowClamp * 128 + k0 + kq;
    float4 xa = *(const float4*)xp;
    float4 xb = *(const float4*)(xp + 4);
    half8 a;
    a[0] = (_Float16)xa.x; a[1] = (_Float16)xa.y; a[2] = (_Float16)xa.z; a[3] = (_Float16)xa.w;
    a[4] = (_Float16)xb.x; a[5] = (_Float16)xb.y; a[6] = (_Float16)xb.z; a[7] = (_Float16)xb.w;
#pragma unroll
    for (int j = 0; j < 8; ++j) {
      half8 b = *(const half8*)(Wt + (size_t)(16 * j + cg) * 128 + k0 + kq);
      acc[j] = __builtin_amdgcn_mfma_f32_16x16x32_f16(a, b, acc[j], 0, 0, 0);
    }
  }

  // epilogue: Hb store (bf16) + logit dots
  float as_[8], ds_[8];
#pragma unroll
  for (int j = 0; j < 8; ++j) { as_[j] = a_src[16 * j + cg]; ds_[j] = a_dst[16 * j + cg]; }
  const int rg = (lane >> 4) * 4;
#pragma unroll
  for (int reg = 0; reg < 4; ++reg) {
    int row = r16 + rg + reg;
    bool ok = row < N;
    float ps = 0.f, pd = 0.f;
#pragma unroll
    for (int j = 0; j < 8; ++j) {
      float v = acc[j][reg];
      if (ok) Hb[(size_t)row * 128 + 16 * j + cg] = f2bf(v);
      ps = fmaf(v, as_[j], ps);
      pd = fmaf(v, ds_[j], pd);
    }
#pragma unroll
    for (int o = 1; o < 16; o <<= 1) { ps += __shfl_xor(ps, o); pd += __shfl_xor(pd, o); }
    if (ok && cg == 0) { asrc[row] = ps; adst[row] = pd; }
  }
}

__global__ __launch_bounds__(256) void gemm2_mfma(
    const _Float16* __restrict__ Xh, const _Float16* __restrict__ Wt,
    const float* __restrict__ a_src_mu, const float* __restrict__ a_dst_mu,
    const float* __restrict__ a_src_ls, const float* __restrict__ a_dst_ls,
    unsigned short* __restrict__ Hb, float* __restrict__ as2, float* __restrict__ ad2, int N) {
  const int wid = threadIdx.x >> 6, lane = threadIdx.x & 63;
  const int r16 = (blockIdx.x * 4 + wid) * 16;
  if (r16 >= N) return;
  const int cg = lane & 15;
  const int kq = (lane >> 4) * 8;
  const int rA = r16 + cg;
  const int rowClamp = min(rA, N - 1);

  f32x4 acc[8];
#pragma unroll
  for (int j = 0; j < 8; ++j) acc[j] = (f32x4){0.f, 0.f, 0.f, 0.f};

#pragma unroll
  for (int ks = 0; ks < 4; ++ks) {
    const int k0 = ks * 32;
    half8 a = *(const half8*)(Xh + (size_t)rowClamp * 128 + k0 + kq);
#pragma unroll
    for (int j = 0; j < 8; ++j) {
      half8 b = *(const half8*)(Wt + (size_t)(16 * j + cg) * 128 + k0 + kq);
      acc[j] = __builtin_amdgcn_mfma_f32_16x16x32_f16(a, b, acc[j], 0, 0, 0);
    }
  }

  // tiles 0-3: mu cols 16j+cg; tiles 4-7: ls cols 16(j-4)+cg
  float asv[8], adv[8];
#pragma unroll
  for (int j = 0; j < 4; ++j) {
    asv[j] = a_src_mu[16 * j + cg]; adv[j] = a_dst_mu[16 * j + cg];
    asv[j + 4] = a_src_ls[16 * j + cg]; adv[j + 4] = a_dst_ls[16 * j + cg];
  }
  const int rg = (lane >> 4) * 4;
#pragma unroll
  for (int reg = 0; reg < 4; ++reg) {
    int row = r16 + rg + reg;
    bool ok = row < N;
    float psm = 0.f, pdm = 0.f, psl = 0.f, pdl = 0.f;
#pragma unroll
    for (int j = 0; j < 8; ++j) {
      float v = acc[j][reg];
      if (ok) Hb[(size_t)row * 128 + 16 * j + cg] = f2bf(v);
      if (j < 4) { psm = fmaf(v, asv[j], psm); pdm = fmaf(v, adv[j], pdm); }
      else       { psl = fmaf(v, asv[j], psl); pdl = fmaf(v, adv[j], pdl); }
    }
#pragma unroll
    for (int o = 1; o < 16; o <<= 1) {
      psm += __shfl_xor(psm, o); pdm += __shfl_xor(pdm, o);
      psl += __shfl_xor(psl, o); pdl += __shfl_xor(pdl, o);
    }
    if (ok && cg == 0) {
      as2[2 * row] = psm; ad2[2 * row] = pdm;
      as2[2 * row + 1] = psl; ad2[2 * row + 1] = pdl;
    }
  }
}

// ---------------- Aggregation layer 1 (bf16 gather, fp32 math, + bias + ReLU, fp16 out) ----------------

__global__ __launch_bounds__(256) void agg1_kernel(
    const unsigned short* __restrict__ Hb, const float* __restrict__ asrc,
    const float* __restrict__ adst,
    const int* __restrict__ row_start, const int* __restrict__ esrc,
    const float* __restrict__ b, _Float16* __restrict__ hout, int N) {
  int lane = threadIdx.x & 63;
  int d = (int)((blockIdx.x * blockDim.x + threadIdx.x) >> 6);
  if (d >= N) return;
  float ad = adst[d];
  float m = leaky02(asrc[d] + ad);
  float denom = 1.0f;
  float2 acc = bfp(((const unsigned*)(Hb + (size_t)d * 128))[lane]);
  int beg = row_start[d], end = row_start[d + 1];
  for (int base = beg; base < end; base += 64) {
    int nv = end - base;
    if (nv > 64) nv = 64;
    float e = -INFINITY;
    int s = 0;
    if (lane < nv) {
      s = esrc[base + lane];
      e = leaky02(asrc[s] + ad);
    }
    float cm = wave_max64(e);
    if (cm > m) {
      float sc = __expf(m - cm);
      denom *= sc; acc.x *= sc; acc.y *= sc;
      m = cm;
    }
    float w = __expf(e - m);
    denom += wave_sum64(w);
    int j = 0;
    for (; j + 4 <= nv; j += 4) {
      int s0 = __shfl(s, j), s1 = __shfl(s, j + 1), s2 = __shfl(s, j + 2), s3 = __shfl(s, j + 3);
      float w0 = __shfl(w, j), w1 = __shfl(w, j + 1), w2 = __shfl(w, j + 2), w3 = __shfl(w, j + 3);
      unsigned v0 = ((const unsigned*)(Hb + (size_t)s0 * 128))[lane];
      unsigned v1 = ((const unsigned*)(Hb + (size_t)s1 * 128))[lane];
      unsigned v2 = ((const unsigned*)(Hb + (size_t)s2 * 128))[lane];
      unsigned v3 = ((const unsigned*)(Hb + (size_t)s3 * 128))[lane];
      float2 f0 = bfp(v0), f1 = bfp(v1), f2 = bfp(v2), f3 = bfp(v3);
      acc.x = fmaf(w0, f0.x, acc.x); acc.y = fmaf(w0, f0.y, acc.y);
      acc.x = fmaf(w1, f1.x, acc.x); acc.y = fmaf(w1, f1.y, acc.y);
      acc.x = fmaf(w2, f2.x, acc.x); acc.y = fmaf(w2, f2.y, acc.y);
      acc.x = fmaf(w3, f3.x, acc.x); acc.y = fmaf(w3, f3.y, acc.y);
    }
    for (; j < nv; ++j) {
      int sj = __shfl(s, j);
      float wj = __shfl(w, j);
      float2 f = bfp(((const unsigned*)(Hb + (size_t)sj * 128))[lane]);
      acc.x = fmaf(wj, f.x, acc.x);
      acc.y = fmaf(wj, f.y, acc.y);
    }
  }
  float inv = 1.0f / denom;
  float2 bv = ((const float2*)b)[lane];
  float ox = fmaxf(fmaf(acc.x, inv, bv.x), 0.0f);
  float oy = fmaxf(fmaf(acc.y, inv, bv.y), 0.0f);
  _Float16 h2[2] = {(_Float16)ox, (_Float16)oy};
  ((unsigned*)(hout + (size_t)d * 128))[lane] = *(unsigned*)h2;
}

// ---------------- Aggregation layers 2+3 fused (mu lanes 0-31, ls lanes 32-63) ----------------

__global__ __launch_bounds__(256) void agg2_kernel(
    const unsigned short* __restrict__ Hb,
    const float2* __restrict__ as2, const float2* __restrict__ ad2,
    const int* __restrict__ row_start, const int* __restrict__ esrc,
    const float* __restrict__ b_mu, const float* __restrict__ b_ls,
    float* __restrict__ out_mu, float* __restrict__ out_ls, int N) {
  int lane = threadIdx.x & 63;
  int d = (int)((blockIdx.x * blockDim.x + threadIdx.x) >> 6);
  if (d >= N) return;
  bool isMu = lane < 32;
  float2 a2d = ad2[d];
  float2 a2s_self = as2[d];
  float m_mu = leaky02(a2s_self.x + a2d.x);
  float m_ls = leaky02(a2s_self.y + a2d.y);
  float den_mu = 1.0f, den_ls = 1.0f;
  float2 acc = bfp(((const unsigned*)(Hb + (size_t)d * 128))[lane]);
  int beg = row_start[d], end = row_start[d + 1];
  for (int base = beg; base < end; base += 64) {
    int nv = end - base;
    if (nv > 64) nv = 64;
    float e_mu = -INFINITY, e_ls = -INFINITY;
    int s = 0;
    if (lane < nv) {
      s = esrc[base + lane];
      float2 av = as2[s];
      e_mu = leaky02(av.x + a2d.x);
      e_ls = leaky02(av.y + a2d.y);
    }
    float cm_mu = wave_max64(e_mu);
    float cm_ls = wave_max64(e_ls);
    float sc_mu = 1.0f, sc_ls = 1.0f;
    if (cm_mu > m_mu) { sc_mu = __expf(m_mu - cm_mu); den_mu *= sc_mu; m_mu = cm_mu; }
    if (cm_ls > m_ls) { sc_ls = __expf(m_ls - cm_ls); den_ls *= sc_ls; m_ls = cm_ls; }
    float sc = isMu ? sc_mu : sc_ls;
    acc.x *= sc; acc.y *= sc;
    float w_mu = __expf(e_mu - m_mu);
    float w_ls = __expf(e_ls - m_ls);
    den_mu += wave_sum64(w_mu);
    den_ls += wave_sum64(w_ls);
    int j = 0;
    for (; j + 4 <= nv; j += 4) {
      int s0 = __shfl(s, j), s1 = __shfl(s, j + 1), s2 = __shfl(s, j + 2), s3 = __shfl(s, j + 3);
      float wm0 = __shfl(w_mu, j), wm1 = __shfl(w_mu, j + 1), wm2 = __shfl(w_mu, j + 2), wm3 = __shfl(w_mu, j + 3);
      float wl0 = __shfl(w_ls, j), wl1 = __shfl(w_ls, j + 1), wl2 = __shfl(w_ls, j + 2), wl3 = __shfl(w_ls, j + 3);
      float w0 = isMu ? wm0 : wl0, w1 = isMu ? wm1 : wl1, w2 = isMu ? wm2 : wl2, w3 = isMu ? wm3 : wl3;
      unsigned v0 = ((const unsigned*)(Hb + (size_t)s0 * 128))[lane];
      unsigned v1 = ((const unsigned*)(Hb + (size_t)s1 * 128))[lane];
      unsigned v2 = ((const unsigned*)(Hb + (size_t)s2 * 128))[lane];
      unsigned v3 = ((const unsigned*)(Hb + (size_t)s3 * 128))[lane];
      float2 f0 = bfp(v0), f1 = bfp(v1), f2 = bfp(v2), f3 = bfp(v3);
      acc.x = fmaf(w0, f0.x, acc.x); acc.y = fmaf(w0, f0.y, acc.y);
      acc.x = fmaf(w1, f1.x, acc.x); acc.y = fmaf(w1, f1.y, acc.y);
      acc.x = fmaf(w2, f2.x, acc.x); acc.y = fmaf(w2, f2.y, acc.y);
      acc.x = fmaf(w3, f3.x, acc.x); acc.y = fmaf(w3, f3.y, acc.y);
    }
    for (; j < nv; ++j) {
      float wj_mu = __shfl(w_mu, j);
      float wj_ls = __shfl(w_ls, j);
      float wj = isMu ? wj_mu : wj_ls;
      int sj = __shfl(s, j);
      float2 f = bfp(((const unsigned*)(Hb + (size_t)sj * 128))[lane]);
      acc.x = fmaf(wj, f.x, acc.x);
      acc.y = fmaf(wj, f.y, acc.y);
    }
  }
  float inv = isMu ? (1.0f / den_mu) : (1.0f / den_ls);
  float2 bv = isMu ? ((const float2*)b_mu)[lane] : ((const float2*)b_ls)[lane - 32];
  float2 o;
  o.x = fmaf(acc.x, inv, bv.x);
  o.y = fmaf(acc.y, inv, bv.y);
  if (isMu) ((float2*)(out_mu + (size_t)d * 64))[lane] = o;
  else      ((float2*)(out_ls + (size_t)d * 64))[lane - 32] = o;
}

// ---------------- launch ----------------

extern "C" void kernel_launch(void* const* d_in, const int* in_sizes, int n_in,
                              void* d_out, int out_size, void* d_ws, size_t ws_size,
                              hipStream_t stream) {
  const float* x = (const float*)d_in[0];
  const int* ei = (const int*)d_in[1];
  const float* W1 = (const float*)d_in[2];
  const float* a_src1 = (const float*)d_in[3];
  const float* a_dst1 = (const float*)d_in[4];
  const float* b1 = (const float*)d_in[5];
  const float* W_mu = (const float*)d_in[6];
  const float* a_src_mu = (const float*)d_in[7];
  const float* a_dst_mu = (const float*)d_in[8];
  const float* b_mu = (const float*)d_in[9];
  const float* W_ls = (const float*)d_in[10];
  const float* a_src_ls = (const float*)d_in[11];
  const float* a_dst_ls = (const float*)d_in[12];
  const float* b_ls = (const float*)d_in[13];

  const int N = in_sizes[0] / 128;  // 50000
  const int E = in_sizes[1] / 2;    // 800000
  const int NBUCK = (N + BDSTS - 1) >> BSHIFT;  // 98 (<=128)

  uint8_t* p = (uint8_t*)d_ws;
  auto carve = [&](size_t bytes) -> void* {
    void* q = (void*)p;
    p += (bytes + 255) & ~(size_t)255;
    return q;
  };
  int* bcount = (int*)carve((size_t)(NBUCK + 1) * 4);
  int* bstart = (int*)carve((size_t)(NBUCK + 1) * 4);
  int* bcursor = (int*)carve((size_t)NBUCK * 4);
  int* row_start = (int*)carve((size_t)(N + 1) * 4);
  int* esrc = (int*)carve((size_t)E * 4);
  int2* pairs = (int2*)carve((size_t)E * 8);
  unsigned short* Hb1 = (unsigned short*)carve((size_t)N * 128 * 2);  // bf16; reused as Hb2
  _Float16* h1 = (_Float16*)carve((size_t)N * 128 * 2);               // fp16 gemm2 input
  _Float16* Wt1 = (_Float16*)carve((size_t)128 * 128 * 2);
  _Float16* Wt2 = (_Float16*)carve((size_t)128 * 128 * 2);
  float* as1 = (float*)carve((size_t)N * 4);
  float* ad1 = (float*)carve((size_t)N * 4);
  float* as2 = (float*)carve((size_t)N * 8);
  float* ad2 = (float*)carve((size_t)N * 8);

  unsigned short* Hb2 = Hb1;

  hipMemsetAsync(bcount, 0, (size_t)(NBUCK + 1) * 4, stream);
  prep_w_kernel<<<64, 256, 0, stream>>>(W1, W_mu, W_ls, Wt1, Wt2);
  bucket_hist_kernel<<<(E + 2047) / 2048, 256, 0, stream>>>(ei, bcount, E, NBUCK);
  bucket_scan_kernel<<<1, 128, 0, stream>>>(bcount, bstart, bcursor, row_start, NBUCK, E, N);
  pair_scatter_kernel<<<(E + CHUNK - 1) / CHUNK, 256, 0, stream>>>(ei, bcursor, pairs, E);
  fine_kernel<<<NBUCK, 512, 0, stream>>>(pairs, bstart, row_start, esrc, N);

  gemm1_mfma<<<(N + 63) / 64, 256, 0, stream>>>(x, Wt1, a_src1, a_dst1, Hb1, as1, ad1, N);
  agg1_kernel<<<(N + 3) / 4, 256, 0, stream>>>(Hb1, as1, ad1, row_start, esrc, b1, h1, N);
  gemm2_mfma<<<(N + 63) / 64, 256, 0, stream>>>(h1, Wt2, a_src_mu, a_dst_mu,
                                                a_src_ls, a_dst_ls, Hb2, as2, ad2, N);
  float* out_mu = (float*)d_out;
  float* out_ls = out_mu + (size_t)N * 64;
  agg2_kernel<<<(N + 3) / 4, 256, 0, stream>>>(Hb2, (const float2*)as2, (const float2*)ad2,
                                               row_start, esrc, b_mu, b_ls, out_mu, out_ls, N);
}

// Round 7
// 165.625 us; speedup vs baseline: 1.3130x; 1.1106x over previous
//
#include <hip/hip_runtime.h>
#include <hip/hip_bf16.h>
#include <math.h>

typedef __attribute__((ext_vector_type(8))) _Float16 half8;
typedef __attribute__((ext_vector_type(4))) float f32x4;

// ---------------- helpers ----------------

__device__ __forceinline__ float leaky02(float v) { return v > 0.0f ? v : 0.2f * v; }

// bf16 pack/unpack (RNE)
__device__ __forceinline__ unsigned short f2bf(float f) {
  unsigned u = __float_as_uint(f);
  u += 0x7FFF + ((u >> 16) & 1);
  return (unsigned short)(u >> 16);
}
__device__ __forceinline__ float2 bfp(unsigned v) {
  float2 r;
  r.x = __uint_as_float(v << 16);
  r.y = __uint_as_float(v & 0xFFFF0000u);
  return r;
}

// ---------------- CSR build: 2-level bucket sort (packed pairs) ----------------

#define BSHIFT 9
#define BDSTS 512

__global__ __launch_bounds__(256) void bucket_hist_kernel(
    const int* __restrict__ ei, int* __restrict__ bcount, int E, int NBUCK) {
  __shared__ int h[128];
  if (threadIdx.x < 128) h[threadIdx.x] = 0;
  __syncthreads();
  for (int e = blockIdx.x * blockDim.x + threadIdx.x; e < E; e += gridDim.x * blockDim.x)
    atomicAdd(&h[ei[E + e] >> BSHIFT], 1);
  __syncthreads();
  if (threadIdx.x < NBUCK && h[threadIdx.x]) atomicAdd(&bcount[threadIdx.x], h[threadIdx.x]);
}

__global__ __launch_bounds__(128) void bucket_scan_kernel(
    const int* __restrict__ bcount, int* __restrict__ bstart, int* __restrict__ bcursor,
    int* __restrict__ row_start, int NBUCK, int E, int N) {
  __shared__ int lds[128];
  int t = threadIdx.x;
  int v = (t < NBUCK) ? bcount[t] : 0;
  lds[t] = v;
  __syncthreads();
#pragma unroll
  for (int off = 1; off < 128; off <<= 1) {
    int tmp = (t >= off) ? lds[t - off] : 0;
    __syncthreads();
    lds[t] += tmp;
    __syncthreads();
  }
  if (t < NBUCK) {
    int excl = lds[t] - v;
    bstart[t] = excl;
    bcursor[t] = excl;
  }
  if (t == 0) { bstart[NBUCK] = E; row_start[N] = E; }
}

#define CHUNK 4096
__global__ __launch_bounds__(256) void pair_scatter_kernel(
    const int* __restrict__ ei, int* __restrict__ bcursor, unsigned* __restrict__ pairs, int E) {
  __shared__ int h[128], base[128], cur[128];
  if (threadIdx.x < 128) { h[threadIdx.x] = 0; cur[threadIdx.x] = 0; }
  __syncthreads();
  int c0 = blockIdx.x * CHUNK;
  int c1 = min(c0 + CHUNK, E);
  for (int e = c0 + (int)threadIdx.x; e < c1; e += 256)
    atomicAdd(&h[ei[E + e] >> BSHIFT], 1);
  __syncthreads();
  if (threadIdx.x < 128 && h[threadIdx.x])
    base[threadIdx.x] = atomicAdd(&bcursor[threadIdx.x], h[threadIdx.x]);
  __syncthreads();
  for (int e = c0 + (int)threadIdx.x; e < c1; e += 256) {
    int dst = ei[E + e];
    int src = ei[e];
    int b = dst >> BSHIFT;
    int r = atomicAdd(&cur[b], 1);
    pairs[base[b] + r] = ((unsigned)src << BSHIFT) | (unsigned)(dst & (BDSTS - 1));
  }
}

__global__ __launch_bounds__(512) void fine_kernel(
    const unsigned* __restrict__ pairs, const int* __restrict__ bstart,
    int* __restrict__ row_start, int* __restrict__ esrc, int N) {
  __shared__ int h[BDSTS], sc[BDSTS], cur[BDSTS];
  int t = threadIdx.x;
  int b = blockIdx.x;
  int d0 = b << BSHIFT;
  int d1 = min(d0 + BDSTS, N);
  int beg = bstart[b], end = bstart[b + 1];
  h[t] = 0;
  __syncthreads();
  for (int i = beg + t; i < end; i += 512) atomicAdd(&h[pairs[i] & (BDSTS - 1)], 1);
  __syncthreads();
  int v = h[t];
  sc[t] = v;
  __syncthreads();
#pragma unroll
  for (int off = 1; off < BDSTS; off <<= 1) {
    int tmp = (t >= off) ? sc[t - off] : 0;
    __syncthreads();
    sc[t] += tmp;
    __syncthreads();
  }
  int excl = sc[t] - v;
  if (d0 + t < d1) row_start[d0 + t] = beg + excl;
  cur[t] = excl;
  __syncthreads();
  for (int i = beg + t; i < end; i += 512) {
    unsigned p = pairs[i];
    int r = atomicAdd(&cur[p & (BDSTS - 1)], 1);
    esrc[beg + r] = (int)(p >> BSHIFT);
  }
}

// ---------------- W prep: fp16 transposed weights ----------------

__global__ __launch_bounds__(256) void prep_w_kernel(
    const float* __restrict__ W1, const float* __restrict__ Wmu, const float* __restrict__ Wls,
    _Float16* __restrict__ Wt1, _Float16* __restrict__ Wt2) {
  int idx = blockIdx.x * 256 + threadIdx.x;  // 16384 total
  int c = idx >> 7, k = idx & 127;
  Wt1[idx] = (_Float16)W1[k * 128 + c];
  float w2 = (c < 64) ? Wmu[k * 64 + c] : Wls[k * 64 + (c - 64)];
  Wt2[idx] = (_Float16)w2;
}

// ---------------- GEMM via MFMA (fp16 in, fp32 acc), no LDS, no barriers ----------------

__global__ __launch_bounds__(256) void gemm1_mfma(
    const float* __restrict__ X, const _Float16* __restrict__ Wt,
    const float* __restrict__ a_src, const float* __restrict__ a_dst,
    unsigned short* __restrict__ Hb, float* __restrict__ asrc, float* __restrict__ adst, int N) {
  const int wid = threadIdx.x >> 6, lane = threadIdx.x & 63;
  const int r16 = (blockIdx.x * 4 + wid) * 16;
  if (r16 >= N) return;
  const int cg = lane & 15;
  const int kq = (lane >> 4) * 8;
  const int rA = r16 + cg;
  const int rowClamp = min(rA, N - 1);

  f32x4 acc[8];
#pragma unroll
  for (int j = 0; j < 8; ++j) acc[j] = (f32x4){0.f, 0.f, 0.f, 0.f};

#pragma unroll
  for (int ks = 0; ks < 4; ++ks) {
    const int k0 = ks * 32;
    const float* xp = X + (size_t)rowClamp * 128 + k0 + kq;
    float4 xa = *(const float4*)xp;
    float4 xb = *(const float4*)(xp + 4);
    half8 a;
    a[0] = (_Float16)xa.x; a[1] = (_Float16)xa.y; a[2] = (_Float16)xa.z; a[3] = (_Float16)xa.w;
    a[4] = (_Float16)xb.x; a[5] = (_Float16)xb.y; a[6] = (_Float16)xb.z; a[7] = (_Float16)xb.w;
#pragma unroll
    for (int j = 0; j < 8; ++j) {
      half8 b = *(const half8*)(Wt + (size_t)(16 * j + cg) * 128 + k0 + kq);
      acc[j] = __builtin_amdgcn_mfma_f32_16x16x32_f16(a, b, acc[j], 0, 0, 0);
    }
  }

  float as_[8], ds_[8];
#pragma unroll
  for (int j = 0; j < 8; ++j) { as_[j] = a_src[16 * j + cg]; ds_[j] = a_dst[16 * j + cg]; }
  const int rg = (lane >> 4) * 4;
#pragma unroll
  for (int reg = 0; reg < 4; ++reg) {
    int row = r16 + rg + reg;
    bool ok = row < N;
    float ps = 0.f, pd = 0.f;
#pragma unroll
    for (int j = 0; j < 8; ++j) {
      float v = acc[j][reg];
      if (ok) Hb[(size_t)row * 128 + 16 * j + cg] = f2bf(v);
      ps = fmaf(v, as_[j], ps);
      pd = fmaf(v, ds_[j], pd);
    }
#pragma unroll
    for (int o = 1; o < 16; o <<= 1) { ps += __shfl_xor(ps, o); pd += __shfl_xor(pd, o); }
    if (ok && cg == 0) { asrc[row] = ps; adst[row] = pd; }
  }
}

__global__ __launch_bounds__(256) void gemm2_mfma(
    const _Float16* __restrict__ Xh, const _Float16* __restrict__ Wt,
    const float* __restrict__ a_src_mu, const float* __restrict__ a_dst_mu,
    const float* __restrict__ a_src_ls, const float* __restrict__ a_dst_ls,
    unsigned short* __restrict__ Hb, float* __restrict__ as2, float* __restrict__ ad2, int N) {
  const int wid = threadIdx.x >> 6, lane = threadIdx.x & 63;
  const int r16 = (blockIdx.x * 4 + wid) * 16;
  if (r16 >= N) return;
  const int cg = lane & 15;
  const int kq = (lane >> 4) * 8;
  const int rA = r16 + cg;
  const int rowClamp = min(rA, N - 1);

  f32x4 acc[8];
#pragma unroll
  for (int j = 0; j < 8; ++j) acc[j] = (f32x4){0.f, 0.f, 0.f, 0.f};

#pragma unroll
  for (int ks = 0; ks < 4; ++ks) {
    const int k0 = ks * 32;
    half8 a = *(const half8*)(Xh + (size_t)rowClamp * 128 + k0 + kq);
#pragma unroll
    for (int j = 0; j < 8; ++j) {
      half8 b = *(const half8*)(Wt + (size_t)(16 * j + cg) * 128 + k0 + kq);
      acc[j] = __builtin_amdgcn_mfma_f32_16x16x32_f16(a, b, acc[j], 0, 0, 0);
    }
  }

  float asv[8], adv[8];
#pragma unroll
  for (int j = 0; j < 4; ++j) {
    asv[j] = a_src_mu[16 * j + cg]; adv[j] = a_dst_mu[16 * j + cg];
    asv[j + 4] = a_src_ls[16 * j + cg]; adv[j + 4] = a_dst_ls[16 * j + cg];
  }
  const int rg = (lane >> 4) * 4;
#pragma unroll
  for (int reg = 0; reg < 4; ++reg) {
    int row = r16 + rg + reg;
    bool ok = row < N;
    float psm = 0.f, pdm = 0.f, psl = 0.f, pdl = 0.f;
#pragma unroll
    for (int j = 0; j < 8; ++j) {
      float v = acc[j][reg];
      if (ok) Hb[(size_t)row * 128 + 16 * j + cg] = f2bf(v);
      if (j < 4) { psm = fmaf(v, asv[j], psm); pdm = fmaf(v, adv[j], pdm); }
      else       { psl = fmaf(v, asv[j], psl); pdl = fmaf(v, adv[j], pdl); }
    }
#pragma unroll
    for (int o = 1; o < 16; o <<= 1) {
      psm += __shfl_xor(psm, o); pdm += __shfl_xor(pdm, o);
      psl += __shfl_xor(psl, o); pdl += __shfl_xor(pdl, o);
    }
    if (ok && cg == 0) {
      as2[2 * row] = psm; ad2[2 * row] = pdm;
      as2[2 * row + 1] = psl; ad2[2 * row + 1] = pdl;
    }
  }
}

// ---------------- Aggregation layer 1: 2 dsts/wave, 4 ch/lane ----------------
// half = lane>>5 selects dst; lane sub=lane&31 owns channels 4*sub..4*sub+3.

__global__ __launch_bounds__(256) void agg1_pv(
    const unsigned short* __restrict__ Hb, const float* __restrict__ asrc,
    const float* __restrict__ adst, const int* __restrict__ row_start,
    const int* __restrict__ esrc, const float* __restrict__ b,
    _Float16* __restrict__ hout, int N) {
  const int lane = threadIdx.x & 63;
  const int half = lane >> 5, sub = lane & 31;
  const int g = (int)(blockIdx.x * 4 + (threadIdx.x >> 6));
  const int d = g * 2 + half;
  const bool dok = d < N;
  const int dc = dok ? d : N - 1;
  const float ad = adst[dc];
  float m = leaky02(asrc[dc] + ad);  // self-loop logit
  float den = 1.0f;
  uint2 sv = *(const uint2*)(Hb + (size_t)dc * 128 + sub * 4);
  float2 f0 = bfp(sv.x), f1 = bfp(sv.y);
  float a0 = f0.x, a1 = f0.y, a2 = f1.x, a3 = f1.y;
  const int beg = row_start[dc];
  const int n = dok ? (row_start[dc + 1] - beg) : 0;
  int nmax = n;
#pragma unroll
  for (int o = 32; o > 0; o >>= 1) nmax = max(nmax, __shfl_xor(nmax, o));
  const int hbase = half * 32;
  for (int c0 = 0; c0 < nmax; c0 += 32) {
    int j = c0 + sub;
    bool v = j < n;
    int s = v ? esrc[beg + j] : dc;
    float e = v ? leaky02(asrc[s] + ad) : -INFINITY;
    float cm = e;
#pragma unroll
    for (int o = 16; o > 0; o >>= 1) cm = fmaxf(cm, __shfl_xor(cm, o));
    float mn = fmaxf(m, cm);
    float sc = __expf(m - mn);
    m = mn;
    den *= sc; a0 *= sc; a1 *= sc; a2 *= sc; a3 *= sc;
    float w = __expf(e - m);  // 0 for invalid lanes
    float ws = w;
#pragma unroll
    for (int o = 16; o > 0; o >>= 1) ws += __shfl_xor(ws, o);
    den += ws;
    int cnt = n - c0; if (cnt > 32) cnt = 32;
    int jj = 0;
    for (; jj + 4 <= cnt; jj += 4) {
      int s0 = __shfl(s, hbase + jj), s1 = __shfl(s, hbase + jj + 1);
      int s2 = __shfl(s, hbase + jj + 2), s3 = __shfl(s, hbase + jj + 3);
      float w0 = __shfl(w, hbase + jj), w1 = __shfl(w, hbase + jj + 1);
      float w2 = __shfl(w, hbase + jj + 2), w3 = __shfl(w, hbase + jj + 3);
      uint2 h0 = *(const uint2*)(Hb + (size_t)s0 * 128 + sub * 4);
      uint2 h1 = *(const uint2*)(Hb + (size_t)s1 * 128 + sub * 4);
      uint2 h2 = *(const uint2*)(Hb + (size_t)s2 * 128 + sub * 4);
      uint2 h3 = *(const uint2*)(Hb + (size_t)s3 * 128 + sub * 4);
      float2 p0 = bfp(h0.x), p1 = bfp(h0.y);
      a0 = fmaf(w0, p0.x, a0); a1 = fmaf(w0, p0.y, a1); a2 = fmaf(w0, p1.x, a2); a3 = fmaf(w0, p1.y, a3);
      p0 = bfp(h1.x); p1 = bfp(h1.y);
      a0 = fmaf(w1, p0.x, a0); a1 = fmaf(w1, p0.y, a1); a2 = fmaf(w1, p1.x, a2); a3 = fmaf(w1, p1.y, a3);
      p0 = bfp(h2.x); p1 = bfp(h2.y);
      a0 = fmaf(w2, p0.x, a0); a1 = fmaf(w2, p0.y, a1); a2 = fmaf(w2, p1.x, a2); a3 = fmaf(w2, p1.y, a3);
      p0 = bfp(h3.x); p1 = bfp(h3.y);
      a0 = fmaf(w3, p0.x, a0); a1 = fmaf(w3, p0.y, a1); a2 = fmaf(w3, p1.x, a2); a3 = fmaf(w3, p1.y, a3);
    }
    for (; jj < cnt; ++jj) {
      int sj = __shfl(s, hbase + jj);
      float wj = __shfl(w, hbase + jj);
      uint2 hv = *(const uint2*)(Hb + (size_t)sj * 128 + sub * 4);
      float2 p0 = bfp(hv.x), p1 = bfp(hv.y);
      a0 = fmaf(wj, p0.x, a0); a1 = fmaf(wj, p0.y, a1);
      a2 = fmaf(wj, p1.x, a2); a3 = fmaf(wj, p1.y, a3);
    }
  }
  if (dok) {
    float inv = 1.0f / den;
    float4 bv = *(const float4*)(b + sub * 4);
    _Float16 o4[4];
    o4[0] = (_Float16)fmaxf(fmaf(a0, inv, bv.x), 0.f);
    o4[1] = (_Float16)fmaxf(fmaf(a1, inv, bv.y), 0.f);
    o4[2] = (_Float16)fmaxf(fmaf(a2, inv, bv.z), 0.f);
    o4[3] = (_Float16)fmaxf(fmaf(a3, inv, bv.w), 0.f);
    *(uint2*)(hout + (size_t)d * 128 + sub * 4) = *(uint2*)o4;
  }
}

// ---------------- Aggregation layers 2+3 fused: 2 dsts/wave, 4 ch/lane ----------------
// sub<16 -> mu channels 4*sub..+3; sub>=16 -> ls channels 4*sub-64..+3.

__global__ __launch_bounds__(256) void agg2_pv(
    const unsigned short* __restrict__ Hb,
    const float2* __restrict__ as2, const float2* __restrict__ ad2,
    const int* __restrict__ row_start, const int* __restrict__ esrc,
    const float* __restrict__ b_mu, const float* __restrict__ b_ls,
    float* __restrict__ out_mu, float* __restrict__ out_ls, int N) {
  const int lane = threadIdx.x & 63;
  const int half = lane >> 5, sub = lane & 31;
  const bool isMu = sub < 16;
  const int g = (int)(blockIdx.x * 4 + (threadIdx.x >> 6));
  const int d = g * 2 + half;
  const bool dok = d < N;
  const int dc = dok ? d : N - 1;
  const float2 adv = ad2[dc];
  const float2 asv = as2[dc];
  float mm = leaky02(asv.x + adv.x);
  float ml = leaky02(asv.y + adv.y);
  float den_m = 1.0f, den_l = 1.0f;
  uint2 sv = *(const uint2*)(Hb + (size_t)dc * 128 + sub * 4);
  float2 f0 = bfp(sv.x), f1 = bfp(sv.y);
  float a0 = f0.x, a1 = f0.y, a2 = f1.x, a3 = f1.y;
  const int beg = row_start[dc];
  const int n = dok ? (row_start[dc + 1] - beg) : 0;
  int nmax = n;
#pragma unroll
  for (int o = 32; o > 0; o >>= 1) nmax = max(nmax, __shfl_xor(nmax, o));
  const int hbase = half * 32;
  for (int c0 = 0; c0 < nmax; c0 += 32) {
    int j = c0 + sub;
    bool v = j < n;
    int s = v ? esrc[beg + j] : dc;
    float em = -INFINITY, el = -INFINITY;
    if (v) {
      float2 av = as2[s];
      em = leaky02(av.x + adv.x);
      el = leaky02(av.y + adv.y);
    }
    float cmm = em, cml = el;
#pragma unroll
    for (int o = 16; o > 0; o >>= 1) {
      cmm = fmaxf(cmm, __shfl_xor(cmm, o));
      cml = fmaxf(cml, __shfl_xor(cml, o));
    }
    float mnm = fmaxf(mm, cmm), mnl = fmaxf(ml, cml);
    float scm = __expf(mm - mnm), scl = __expf(ml - mnl);
    mm = mnm; ml = mnl;
    den_m *= scm; den_l *= scl;
    float sce = isMu ? scm : scl;
    a0 *= sce; a1 *= sce; a2 *= sce; a3 *= sce;
    float wm = __expf(em - mm), wl = __expf(el - ml);
    float wsm = wm, wsl = wl;
#pragma unroll
    for (int o = 16; o > 0; o >>= 1) {
      wsm += __shfl_xor(wsm, o);
      wsl += __shfl_xor(wsl, o);
    }
    den_m += wsm; den_l += wsl;
    int cnt = n - c0; if (cnt > 32) cnt = 32;
    int jj = 0;
    for (; jj + 4 <= cnt; jj += 4) {
      int s0 = __shfl(s, hbase + jj), s1 = __shfl(s, hbase + jj + 1);
      int s2 = __shfl(s, hbase + jj + 2), s3 = __shfl(s, hbase + jj + 3);
      float wm0 = __shfl(wm, hbase + jj), wm1 = __shfl(wm, hbase + jj + 1);
      float wm2 = __shfl(wm, hbase + jj + 2), wm3 = __shfl(wm, hbase + jj + 3);
      float wl0 = __shfl(wl, hbase + jj), wl1 = __shfl(wl, hbase + jj + 1);
      float wl2 = __shfl(wl, hbase + jj + 2), wl3 = __shfl(wl, hbase + jj + 3);
      float w0 = isMu ? wm0 : wl0, w1 = isMu ? wm1 : wl1;
      float w2 = isMu ? wm2 : wl2, w3 = isMu ? wm3 : wl3;
      uint2 h0 = *(const uint2*)(Hb + (size_t)s0 * 128 + sub * 4);
      uint2 h1 = *(const uint2*)(Hb + (size_t)s1 * 128 + sub * 4);
      uint2 h2 = *(const uint2*)(Hb + (size_t)s2 * 128 + sub * 4);
      uint2 h3 = *(const uint2*)(Hb + (size_t)s3 * 128 + sub * 4);
      float2 p0 = bfp(h0.x), p1 = bfp(h0.y);
      a0 = fmaf(w0, p0.x, a0); a1 = fmaf(w0, p0.y, a1); a2 = fmaf(w0, p1.x, a2); a3 = fmaf(w0, p1.y, a3);
      p0 = bfp(h1.x); p1 = bfp(h1.y);
      a0 = fmaf(w1, p0.x, a0); a1 = fmaf(w1, p0.y, a1); a2 = fmaf(w1, p1.x, a2); a3 = fmaf(w1, p1.y, a3);
      p0 = bfp(h2.x); p1 = bfp(h2.y);
      a0 = fmaf(w2, p0.x, a0); a1 = fmaf(w2, p0.y, a1); a2 = fmaf(w2, p1.x, a2); a3 = fmaf(w2, p1.y, a3);
      p0 = bfp(h3.x); p1 = bfp(h3.y);
      a0 = fmaf(w3, p0.x, a0); a1 = fmaf(w3, p0.y, a1); a2 = fmaf(w3, p1.x, a2); a3 = fmaf(w3, p1.y, a3);
    }
    for (; jj < cnt; ++jj) {
      int sj = __shfl(s, hbase + jj);
      float wmj = __shfl(wm, hbase + jj);
      float wlj = __shfl(wl, hbase + jj);
      float wj = isMu ? wmj : wlj;
      uint2 hv = *(const uint2*)(Hb + (size_t)sj * 128 + sub * 4);
      float2 p0 = bfp(hv.x), p1 = bfp(hv.y);
      a0 = fmaf(wj, p0.x, a0); a1 = fmaf(wj, p0.y, a1);
      a2 = fmaf(wj, p1.x, a2); a3 = fmaf(wj, p1.y, a3);
    }
  }
  if (dok) {
    float inv = isMu ? (1.0f / den_m) : (1.0f / den_l);
    const float* bp;
    float* op;
    if (isMu) { bp = b_mu + sub * 4; op = out_mu + (size_t)d * 64 + sub * 4; }
    else      { bp = b_ls + sub * 4 - 64; op = out_ls + (size_t)d * 64 + sub * 4 - 64; }
    float4 bv = *(const float4*)bp;
    float4 o;
    o.x = fmaf(a0, inv, bv.x);
    o.y = fmaf(a1, inv, bv.y);
    o.z = fmaf(a2, inv, bv.z);
    o.w = fmaf(a3, inv, bv.w);
    *(float4*)op = o;
  }
}

// ---------------- launch ----------------

extern "C" void kernel_launch(void* const* d_in, const int* in_sizes, int n_in,
                              void* d_out, int out_size, void* d_ws, size_t ws_size,
                              hipStream_t stream) {
  const float* x = (const float*)d_in[0];
  const int* ei = (const int*)d_in[1];
  const float* W1 = (const float*)d_in[2];
  const float* a_src1 = (const float*)d_in[3];
  const float* a_dst1 = (const float*)d_in[4];
  const float* b1 = (const float*)d_in[5];
  const float* W_mu = (const float*)d_in[6];
  const float* a_src_mu = (const float*)d_in[7];
  const float* a_dst_mu = (const float*)d_in[8];
  const float* b_mu = (const float*)d_in[9];
  const float* W_ls = (const float*)d_in[10];
  const float* a_src_ls = (const float*)d_in[11];
  const float* a_dst_ls = (const float*)d_in[12];
  const float* b_ls = (const float*)d_in[13];

  const int N = in_sizes[0] / 128;  // 50000
  const int E = in_sizes[1] / 2;    // 800000
  const int NBUCK = (N + BDSTS - 1) >> BSHIFT;  // 98 (<=128)

  uint8_t* p = (uint8_t*)d_ws;
  auto carve = [&](size_t bytes) -> void* {
    void* q = (void*)p;
    p += (bytes + 255) & ~(size_t)255;
    return q;
  };
  int* bcount = (int*)carve((size_t)(NBUCK + 1) * 4);
  int* bstart = (int*)carve((size_t)(NBUCK + 1) * 4);
  int* bcursor = (int*)carve((size_t)NBUCK * 4);
  int* row_start = (int*)carve((size_t)(N + 1) * 4);
  int* esrc = (int*)carve((size_t)E * 4);
  unsigned* pairs = (unsigned*)carve((size_t)E * 4);
  unsigned short* Hb1 = (unsigned short*)carve((size_t)N * 128 * 2);  // bf16; reused as Hb2
  _Float16* h1 = (_Float16*)carve((size_t)N * 128 * 2);               // fp16 gemm2 input
  _Float16* Wt1 = (_Float16*)carve((size_t)128 * 128 * 2);
  _Float16* Wt2 = (_Float16*)carve((size_t)128 * 128 * 2);
  float* as1 = (float*)carve((size_t)N * 4);
  float* ad1 = (float*)carve((size_t)N * 4);
  float* as2 = (float*)carve((size_t)N * 8);
  float* ad2 = (float*)carve((size_t)N * 8);

  unsigned short* Hb2 = Hb1;

  hipMemsetAsync(bcount, 0, (size_t)(NBUCK + 1) * 4, stream);
  prep_w_kernel<<<64, 256, 0, stream>>>(W1, W_mu, W_ls, Wt1, Wt2);
  bucket_hist_kernel<<<(E + 2047) / 2048, 256, 0, stream>>>(ei, bcount, E, NBUCK);
  bucket_scan_kernel<<<1, 128, 0, stream>>>(bcount, bstart, bcursor, row_start, NBUCK, E, N);
  pair_scatter_kernel<<<(E + CHUNK - 1) / CHUNK, 256, 0, stream>>>(ei, bcursor, pairs, E);
  fine_kernel<<<NBUCK, 512, 0, stream>>>(pairs, bstart, row_start, esrc, N);

  gemm1_mfma<<<(N + 63) / 64, 256, 0, stream>>>(x, Wt1, a_src1, a_dst1, Hb1, as1, ad1, N);
  const int nwaves = (N + 1) / 2;
  const int nblk = (nwaves + 3) / 4;
  agg1_pv<<<nblk, 256, 0, stream>>>(Hb1, as1, ad1, row_start, esrc, b1, h1, N);
  gemm2_mfma<<<(N + 63) / 64, 256, 0, stream>>>(h1, Wt2, a_src_mu, a_dst_mu,
                                                a_src_ls, a_dst_ls, Hb2, as2, ad2, N);
  float* out_mu = (float*)d_out;
  float* out_ls = out_mu + (size_t)N * 64;
  agg2_pv<<<nblk, 256, 0, stream>>>(Hb2, (const float2*)as2, (const float2*)ad2,
                                    row_start, esrc, b_mu, b_ls, out_mu, out_ls, N);
}

// Round 8
// 163.405 us; speedup vs baseline: 1.3309x; 1.0136x over previous
//
#include <hip/hip_runtime.h>
#include <hip/hip_bf16.h>
#include <math.h>

typedef __attribute__((ext_vector_type(8))) _Float16 half8;
typedef __attribute__((ext_vector_type(4))) float f32x4;

// ---------------- helpers ----------------

__device__ __forceinline__ float leaky02(float v) { return v > 0.0f ? v : 0.2f * v; }

// bf16 pack/unpack (RNE)
__device__ __forceinline__ unsigned short f2bf(float f) {
  unsigned u = __float_as_uint(f);
  u += 0x7FFF + ((u >> 16) & 1);
  return (unsigned short)(u >> 16);
}
__device__ __forceinline__ float2 bfp(unsigned v) {
  float2 r;
  r.x = __uint_as_float(v << 16);
  r.y = __uint_as_float(v & 0xFFFF0000u);
  return r;
}

// ---------------- CSR build: 2-level bucket sort (256 dsts/bucket) ----------------

#define BSHIFT 8
#define BDSTS 256

__global__ __launch_bounds__(256) void bucket_scan_kernel(
    const int* __restrict__ bcount, int* __restrict__ bstart, int* __restrict__ bcursor,
    int* __restrict__ row_start, int NBUCK, int E, int N) {
  __shared__ int lds[256];
  int t = threadIdx.x;
  int v = (t < NBUCK) ? bcount[t] : 0;
  lds[t] = v;
  __syncthreads();
#pragma unroll
  for (int off = 1; off < 256; off <<= 1) {
    int tmp = (t >= off) ? lds[t - off] : 0;
    __syncthreads();
    lds[t] += tmp;
    __syncthreads();
  }
  if (t < NBUCK) {
    int excl = lds[t] - v;
    bstart[t] = excl;
    bcursor[t] = excl;
  }
  if (t == 0) { bstart[NBUCK] = E; row_start[N] = E; }
}

#define CHUNK 4096
__global__ __launch_bounds__(256) void pair_scatter_kernel(
    const int* __restrict__ ei, int* __restrict__ bcursor, unsigned* __restrict__ pairs, int E) {
  __shared__ int h[256], base[256], cur[256];
  h[threadIdx.x] = 0; cur[threadIdx.x] = 0;
  __syncthreads();
  int c0 = blockIdx.x * CHUNK;
  int c1 = min(c0 + CHUNK, E);
  for (int e = c0 + (int)threadIdx.x; e < c1; e += 256)
    atomicAdd(&h[ei[E + e] >> BSHIFT], 1);
  __syncthreads();
  if (h[threadIdx.x])
    base[threadIdx.x] = atomicAdd(&bcursor[threadIdx.x], h[threadIdx.x]);
  __syncthreads();
  for (int e = c0 + (int)threadIdx.x; e < c1; e += 256) {
    int dst = ei[E + e];
    int src = ei[e];
    int b = dst >> BSHIFT;
    int r = atomicAdd(&cur[b], 1);
    pairs[base[b] + r] = ((unsigned)src << BSHIFT) | (unsigned)(dst & (BDSTS - 1));
  }
}

__global__ __launch_bounds__(256) void fine_kernel(
    const unsigned* __restrict__ pairs, const int* __restrict__ bstart,
    int* __restrict__ row_start, int* __restrict__ esrc, int N) {
  __shared__ int h[BDSTS], sc[BDSTS], cur[BDSTS];
  int t = threadIdx.x;
  int b = blockIdx.x;
  int d0 = b << BSHIFT;
  int beg = bstart[b], end = bstart[b + 1];
  h[t] = 0;
  __syncthreads();
  for (int i = beg + t; i < end; i += 256) atomicAdd(&h[pairs[i] & (BDSTS - 1)], 1);
  __syncthreads();
  int v = h[t];
  sc[t] = v;
  __syncthreads();
#pragma unroll
  for (int off = 1; off < BDSTS; off <<= 1) {
    int tmp = (t >= off) ? sc[t - off] : 0;
    __syncthreads();
    sc[t] += tmp;
    __syncthreads();
  }
  int excl = sc[t] - v;
  if (d0 + t < N) row_start[d0 + t] = beg + excl;
  cur[t] = excl;
  __syncthreads();
  for (int i = beg + t; i < end; i += 256) {
    unsigned p = pairs[i];
    int r = atomicAdd(&cur[p & (BDSTS - 1)], 1);
    esrc[beg + r] = (int)(p >> BSHIFT);
  }
}

// ---------------- W prep: fp16 transposed weights ----------------

__global__ __launch_bounds__(256) void prep_w_kernel(
    const float* __restrict__ W1, const float* __restrict__ Wmu, const float* __restrict__ Wls,
    _Float16* __restrict__ Wt1, _Float16* __restrict__ Wt2) {
  int idx = blockIdx.x * 256 + threadIdx.x;  // 16384 total
  int c = idx >> 7, k = idx & 127;
  Wt1[idx] = (_Float16)W1[k * 128 + c];
  float w2 = (c < 64) ? Wmu[k * 64 + c] : Wls[k * 64 + (c - 64)];
  Wt2[idx] = (_Float16)w2;
}

// ---------------- GEMM1 via MFMA, fused with bucket_hist ----------------
// blocks [0, nGB): gemm1; blocks [nGB, nGB+nHB): histogram of dst buckets.

__global__ __launch_bounds__(256) void gemm1_hist(
    const float* __restrict__ X, const _Float16* __restrict__ Wt,
    const float* __restrict__ a_src, const float* __restrict__ a_dst,
    unsigned short* __restrict__ Hb, float* __restrict__ asrc, float* __restrict__ adst, int N,
    const int* __restrict__ ei, int* __restrict__ bcount, int E, int nGB) {
  if ((int)blockIdx.x >= nGB) {
    // ---- histogram part ----
    __shared__ int h[256];
    h[threadIdx.x] = 0;
    __syncthreads();
    int hb = (int)blockIdx.x - nGB;
    int c0 = hb * 2048;
    int c1 = min(c0 + 2048, E);
    for (int e = c0 + (int)threadIdx.x; e < c1; e += 256)
      atomicAdd(&h[ei[E + e] >> BSHIFT], 1);
    __syncthreads();
    if (h[threadIdx.x]) atomicAdd(&bcount[threadIdx.x], h[threadIdx.x]);
    return;
  }
  const int wid = threadIdx.x >> 6, lane = threadIdx.x & 63;
  const int r16 = ((int)blockIdx.x * 4 + wid) * 16;
  if (r16 >= N) return;
  const int cg = lane & 15;
  const int kq = (lane >> 4) * 8;
  const int rA = r16 + cg;
  const int rowClamp = min(rA, N - 1);

  f32x4 acc[8];
#pragma unroll
  for (int j = 0; j < 8; ++j) acc[j] = (f32x4){0.f, 0.f, 0.f, 0.f};

#pragma unroll
  for (int ks = 0; ks < 4; ++ks) {
    const int k0 = ks * 32;
    const float* xp = X + (size_t)rowClamp * 128 + k0 + kq;
    float4 xa = *(const float4*)xp;
    float4 xb = *(const float4*)(xp + 4);
    half8 a;
    a[0] = (_Float16)xa.x; a[1] = (_Float16)xa.y; a[2] = (_Float16)xa.z; a[3] = (_Float16)xa.w;
    a[4] = (_Float16)xb.x; a[5] = (_Float16)xb.y; a[6] = (_Float16)xb.z; a[7] = (_Float16)xb.w;
#pragma unroll
    for (int j = 0; j < 8; ++j) {
      half8 b = *(const half8*)(Wt + (size_t)(16 * j + cg) * 128 + k0 + kq);
      acc[j] = __builtin_amdgcn_mfma_f32_16x16x32_f16(a, b, acc[j], 0, 0, 0);
    }
  }

  float as_[8], ds_[8];
#pragma unroll
  for (int j = 0; j < 8; ++j) { as_[j] = a_src[16 * j + cg]; ds_[j] = a_dst[16 * j + cg]; }
  const int rg = (lane >> 4) * 4;
#pragma unroll
  for (int reg = 0; reg < 4; ++reg) {
    int row = r16 + rg + reg;
    bool ok = row < N;
    float ps = 0.f, pd = 0.f;
#pragma unroll
    for (int j = 0; j < 8; ++j) {
      float v = acc[j][reg];
      if (ok) Hb[(size_t)row * 128 + 16 * j + cg] = f2bf(v);
      ps = fmaf(v, as_[j], ps);
      pd = fmaf(v, ds_[j], pd);
    }
#pragma unroll
    for (int o = 1; o < 16; o <<= 1) { ps += __shfl_xor(ps, o); pd += __shfl_xor(pd, o); }
    if (ok && cg == 0) { asrc[row] = ps; adst[row] = pd; }
  }
}

__global__ __launch_bounds__(256) void gemm2_mfma(
    const _Float16* __restrict__ Xh, const _Float16* __restrict__ Wt,
    const float* __restrict__ a_src_mu, const float* __restrict__ a_dst_mu,
    const float* __restrict__ a_src_ls, const float* __restrict__ a_dst_ls,
    unsigned short* __restrict__ Hb, float* __restrict__ as2, float* __restrict__ ad2, int N) {
  const int wid = threadIdx.x >> 6, lane = threadIdx.x & 63;
  const int r16 = ((int)blockIdx.x * 4 + wid) * 16;
  if (r16 >= N) return;
  const int cg = lane & 15;
  const int kq = (lane >> 4) * 8;
  const int rA = r16 + cg;
  const int rowClamp = min(rA, N - 1);

  f32x4 acc[8];
#pragma unroll
  for (int j = 0; j < 8; ++j) acc[j] = (f32x4){0.f, 0.f, 0.f, 0.f};

#pragma unroll
  for (int ks = 0; ks < 4; ++ks) {
    const int k0 = ks * 32;
    half8 a = *(const half8*)(Xh + (size_t)rowClamp * 128 + k0 + kq);
#pragma unroll
    for (int j = 0; j < 8; ++j) {
      half8 b = *(const half8*)(Wt + (size_t)(16 * j + cg) * 128 + k0 + kq);
      acc[j] = __builtin_amdgcn_mfma_f32_16x16x32_f16(a, b, acc[j], 0, 0, 0);
    }
  }

  float asv[8], adv[8];
#pragma unroll
  for (int j = 0; j < 4; ++j) {
    asv[j] = a_src_mu[16 * j + cg]; adv[j] = a_dst_mu[16 * j + cg];
    asv[j + 4] = a_src_ls[16 * j + cg]; adv[j + 4] = a_dst_ls[16 * j + cg];
  }
  const int rg = (lane >> 4) * 4;
#pragma unroll
  for (int reg = 0; reg < 4; ++reg) {
    int row = r16 + rg + reg;
    bool ok = row < N;
    float psm = 0.f, pdm = 0.f, psl = 0.f, pdl = 0.f;
#pragma unroll
    for (int j = 0; j < 8; ++j) {
      float v = acc[j][reg];
      if (ok) Hb[(size_t)row * 128 + 16 * j + cg] = f2bf(v);
      if (j < 4) { psm = fmaf(v, asv[j], psm); pdm = fmaf(v, adv[j], pdm); }
      else       { psl = fmaf(v, asv[j], psl); pdl = fmaf(v, adv[j], pdl); }
    }
#pragma unroll
    for (int o = 1; o < 16; o <<= 1) {
      psm += __shfl_xor(psm, o); pdm += __shfl_xor(pdm, o);
      psl += __shfl_xor(psl, o); pdl += __shfl_xor(pdl, o);
    }
    if (ok && cg == 0) {
      as2[2 * row] = psm; ad2[2 * row] = pdm;
      as2[2 * row + 1] = psl; ad2[2 * row + 1] = pdl;
    }
  }
}

// ---------------- Aggregation layer 1: no-max softmax, 2 dsts/wave, 4 ch/lane ----------------

#define GATH(K)                                                          \
  {                                                                      \
    int sA = __shfl(s, hbase + jj + K);                                  \
    float wA = __shfl(w, hbase + jj + K);                                \
    uint2 hA = *(const uint2*)(Hb + (size_t)sA * 128 + sub * 4);         \
    float2 pa = bfp(hA.x), pb = bfp(hA.y);                               \
    a0 = fmaf(wA, pa.x, a0); a1 = fmaf(wA, pa.y, a1);                    \
    a2 = fmaf(wA, pb.x, a2); a3 = fmaf(wA, pb.y, a3);                    \
  }

__global__ __launch_bounds__(256) void agg1_ns(
    const unsigned short* __restrict__ Hb, const float* __restrict__ asrc,
    const float* __restrict__ adst, const int* __restrict__ row_start,
    const int* __restrict__ esrc, const float* __restrict__ b,
    _Float16* __restrict__ hout, int N) {
  const int lane = threadIdx.x & 63;
  const int half = lane >> 5, sub = lane & 31;
  const int g = (int)(blockIdx.x * 4 + (threadIdx.x >> 6));
  const int d = g * 2 + half;
  const bool dok = d < N;
  const int dc = dok ? d : N - 1;
  const float ad = adst[dc];
  const float wself = __expf(leaky02(asrc[dc] + ad));
  uint2 sv = *(const uint2*)(Hb + (size_t)dc * 128 + sub * 4);
  float2 f0 = bfp(sv.x), f1 = bfp(sv.y);
  float a0 = wself * f0.x, a1 = wself * f0.y, a2 = wself * f1.x, a3 = wself * f1.y;
  float den = (sub == 0) ? wself : 0.f;
  const int beg = row_start[dc];
  const int n = dok ? (row_start[dc + 1] - beg) : 0;
  const int nmax = max(n, __shfl_xor(n, 32));
  const int hbase = half * 32;
  for (int c0 = 0; c0 < nmax; c0 += 32) {
    int j = c0 + sub;
    bool v = j < n;
    int s = v ? esrc[beg + j] : 0;
    float w = 0.f;
    if (v) w = __expf(leaky02(asrc[s] + ad));
    den += w;
    int cnt = n - c0;
    if (cnt > 32) cnt = 32;
    if (cnt < 0) cnt = 0;
    int jj = 0;
    for (; jj + 8 <= cnt; jj += 8) {
      GATH(0) GATH(1) GATH(2) GATH(3) GATH(4) GATH(5) GATH(6) GATH(7)
    }
    for (; jj < cnt; ++jj) GATH(0)
  }
#pragma unroll
  for (int o = 16; o > 0; o >>= 1) den += __shfl_xor(den, o);
  if (dok) {
    float inv = 1.0f / den;
    float4 bv = *(const float4*)(b + sub * 4);
    _Float16 o4[4];
    o4[0] = (_Float16)fmaxf(fmaf(a0, inv, bv.x), 0.f);
    o4[1] = (_Float16)fmaxf(fmaf(a1, inv, bv.y), 0.f);
    o4[2] = (_Float16)fmaxf(fmaf(a2, inv, bv.z), 0.f);
    o4[3] = (_Float16)fmaxf(fmaf(a3, inv, bv.w), 0.f);
    *(uint2*)(hout + (size_t)d * 128 + sub * 4) = *(uint2*)o4;
  }
}

// ---------------- Aggregation layers 2+3 fused: no-max softmax ----------------

#define GATH2(K)                                                         \
  {                                                                      \
    int sA = __shfl(s, hbase + jj + K);                                  \
    float wmA = __shfl(wm, hbase + jj + K);                              \
    float wlA = __shfl(wl, hbase + jj + K);                              \
    float wA = isMu ? wmA : wlA;                                         \
    uint2 hA = *(const uint2*)(Hb + (size_t)sA * 128 + sub * 4);         \
    float2 pa = bfp(hA.x), pb = bfp(hA.y);                               \
    a0 = fmaf(wA, pa.x, a0); a1 = fmaf(wA, pa.y, a1);                    \
    a2 = fmaf(wA, pb.x, a2); a3 = fmaf(wA, pb.y, a3);                    \
  }

__global__ __launch_bounds__(256) void agg2_ns(
    const unsigned short* __restrict__ Hb,
    const float2* __restrict__ as2, const float2* __restrict__ ad2,
    const int* __restrict__ row_start, const int* __restrict__ esrc,
    const float* __restrict__ b_mu, const float* __restrict__ b_ls,
    float* __restrict__ out_mu, float* __restrict__ out_ls, int N) {
  const int lane = threadIdx.x & 63;
  const int half = lane >> 5, sub = lane & 31;
  const bool isMu = sub < 16;
  const int g = (int)(blockIdx.x * 4 + (threadIdx.x >> 6));
  const int d = g * 2 + half;
  const bool dok = d < N;
  const int dc = dok ? d : N - 1;
  const float2 adv = ad2[dc];
  const float2 asv = as2[dc];
  const float wself_m = __expf(leaky02(asv.x + adv.x));
  const float wself_l = __expf(leaky02(asv.y + adv.y));
  uint2 sv = *(const uint2*)(Hb + (size_t)dc * 128 + sub * 4);
  float2 f0 = bfp(sv.x), f1 = bfp(sv.y);
  const float wself = isMu ? wself_m : wself_l;
  float a0 = wself * f0.x, a1 = wself * f0.y, a2 = wself * f1.x, a3 = wself * f1.y;
  float den_m = (sub == 0) ? wself_m : 0.f;
  float den_l = (sub == 0) ? wself_l : 0.f;
  const int beg = row_start[dc];
  const int n = dok ? (row_start[dc + 1] - beg) : 0;
  const int nmax = max(n, __shfl_xor(n, 32));
  const int hbase = half * 32;
  for (int c0 = 0; c0 < nmax; c0 += 32) {
    int j = c0 + sub;
    bool v = j < n;
    int s = v ? esrc[beg + j] : 0;
    float wm = 0.f, wl = 0.f;
    if (v) {
      float2 av = as2[s];
      wm = __expf(leaky02(av.x + adv.x));
      wl = __expf(leaky02(av.y + adv.y));
    }
    den_m += wm;
    den_l += wl;
    int cnt = n - c0;
    if (cnt > 32) cnt = 32;
    if (cnt < 0) cnt = 0;
    int jj = 0;
    for (; jj + 8 <= cnt; jj += 8) {
      GATH2(0) GATH2(1) GATH2(2) GATH2(3) GATH2(4) GATH2(5) GATH2(6) GATH2(7)
    }
    for (; jj < cnt; ++jj) GATH2(0)
  }
#pragma unroll
  for (int o = 16; o > 0; o >>= 1) {
    den_m += __shfl_xor(den_m, o);
    den_l += __shfl_xor(den_l, o);
  }
  if (dok) {
    float inv = isMu ? (1.0f / den_m) : (1.0f / den_l);
    const float* bp;
    float* op;
    if (isMu) { bp = b_mu + sub * 4; op = out_mu + (size_t)d * 64 + sub * 4; }
    else      { bp = b_ls + sub * 4 - 64; op = out_ls + (size_t)d * 64 + sub * 4 - 64; }
    float4 bv = *(const float4*)bp;
    float4 o;
    o.x = fmaf(a0, inv, bv.x);
    o.y = fmaf(a1, inv, bv.y);
    o.z = fmaf(a2, inv, bv.z);
    o.w = fmaf(a3, inv, bv.w);
    *(float4*)op = o;
  }
}

// ---------------- launch ----------------

extern "C" void kernel_launch(void* const* d_in, const int* in_sizes, int n_in,
                              void* d_out, int out_size, void* d_ws, size_t ws_size,
                              hipStream_t stream) {
  const float* x = (const float*)d_in[0];
  const int* ei = (const int*)d_in[1];
  const float* W1 = (const float*)d_in[2];
  const float* a_src1 = (const float*)d_in[3];
  const float* a_dst1 = (const float*)d_in[4];
  const float* b1 = (const float*)d_in[5];
  const float* W_mu = (const float*)d_in[6];
  const float* a_src_mu = (const float*)d_in[7];
  const float* a_dst_mu = (const float*)d_in[8];
  const float* b_mu = (const float*)d_in[9];
  const float* W_ls = (const float*)d_in[10];
  const float* a_src_ls = (const float*)d_in[11];
  const float* a_dst_ls = (const float*)d_in[12];
  const float* b_ls = (const float*)d_in[13];

  const int N = in_sizes[0] / 128;  // 50000
  const int E = in_sizes[1] / 2;    // 800000
  const int NBUCK = (N + BDSTS - 1) >> BSHIFT;  // 196 (<=256)

  uint8_t* p = (uint8_t*)d_ws;
  auto carve = [&](size_t bytes) -> void* {
    void* q = (void*)p;
    p += (bytes + 255) & ~(size_t)255;
    return q;
  };
  int* bcount = (int*)carve((size_t)(NBUCK + 1) * 4);
  int* bstart = (int*)carve((size_t)(NBUCK + 1) * 4);
  int* bcursor = (int*)carve((size_t)NBUCK * 4);
  int* row_start = (int*)carve((size_t)(N + 1) * 4);
  int* esrc = (int*)carve((size_t)E * 4);
  unsigned* pairs = (unsigned*)carve((size_t)E * 4);
  unsigned short* Hb1 = (unsigned short*)carve((size_t)N * 128 * 2);  // bf16; reused as Hb2
  _Float16* h1 = (_Float16*)carve((size_t)N * 128 * 2);               // fp16 gemm2 input
  _Float16* Wt1 = (_Float16*)carve((size_t)128 * 128 * 2);
  _Float16* Wt2 = (_Float16*)carve((size_t)128 * 128 * 2);
  float* as1 = (float*)carve((size_t)N * 4);
  float* ad1 = (float*)carve((size_t)N * 4);
  float* as2 = (float*)carve((size_t)N * 8);
  float* ad2 = (float*)carve((size_t)N * 8);

  unsigned short* Hb2 = Hb1;

  hipMemsetAsync(bcount, 0, (size_t)(NBUCK + 1) * 4, stream);
  prep_w_kernel<<<64, 256, 0, stream>>>(W1, W_mu, W_ls, Wt1, Wt2);

  const int nGB = (N + 63) / 64;          // gemm1 blocks
  const int nHB = (E + 2047) / 2048;      // hist blocks
  gemm1_hist<<<nGB + nHB, 256, 0, stream>>>(x, Wt1, a_src1, a_dst1, Hb1, as1, ad1, N,
                                            ei, bcount, E, nGB);
  bucket_scan_kernel<<<1, 256, 0, stream>>>(bcount, bstart, bcursor, row_start, NBUCK, E, N);
  pair_scatter_kernel<<<(E + CHUNK - 1) / CHUNK, 256, 0, stream>>>(ei, bcursor, pairs, E);
  fine_kernel<<<NBUCK, 256, 0, stream>>>(pairs, bstart, row_start, esrc, N);

  const int nwaves = (N + 1) / 2;
  const int nblk = (nwaves + 3) / 4;
  agg1_ns<<<nblk, 256, 0, stream>>>(Hb1, as1, ad1, row_start, esrc, b1, h1, N);
  gemm2_mfma<<<(N + 63) / 64, 256, 0, stream>>>(h1, Wt2, a_src_mu, a_dst_mu,
                                                a_src_ls, a_dst_ls, Hb2, as2, ad2, N);
  float* out_mu = (float*)d_out;
  float* out_ls = out_mu + (size_t)N * 64;
  agg2_ns<<<nblk, 256, 0, stream>>>(Hb2, (const float2*)as2, (const float2*)ad2,
                                    row_start, esrc, b_mu, b_ls, out_mu, out_ls, N);
}

// Round 9
// 161.302 us; speedup vs baseline: 1.3482x; 1.0130x over previous
//
#include <hip/hip_runtime.h>
#include <hip/hip_bf16.h>
#include <math.h>

typedef __attribute__((ext_vector_type(8))) _Float16 half8;
typedef __attribute__((ext_vector_type(4))) float f32x4;

// ---------------- helpers ----------------

__device__ __forceinline__ float leaky02(float v) { return v > 0.0f ? v : 0.2f * v; }

__device__ __forceinline__ unsigned short f2bf(float f) {
  unsigned u = __float_as_uint(f);
  u += 0x7FFF + ((u >> 16) & 1);
  return (unsigned short)(u >> 16);
}
__device__ __forceinline__ float2 bfp(unsigned v) {
  float2 r;
  r.x = __uint_as_float(v << 16);
  r.y = __uint_as_float(v & 0xFFFF0000u);
  return r;
}

// ---------------- CSR build: 2-level bucket sort (256 dsts/bucket) ----------------

#define BSHIFT 8
#define BDSTS 256

#define CHUNK 4096
__global__ __launch_bounds__(256) void pair_scatter_kernel(
    const int* __restrict__ ei, int* __restrict__ bcursor, unsigned* __restrict__ pairs, int E) {
  __shared__ int h[256], base[256], cur[256];
  h[threadIdx.x] = 0; cur[threadIdx.x] = 0;
  __syncthreads();
  int c0 = blockIdx.x * CHUNK;
  int c1 = min(c0 + CHUNK, E);
  for (int e = c0 + (int)threadIdx.x; e < c1; e += 256)
    atomicAdd(&h[ei[E + e] >> BSHIFT], 1);
  __syncthreads();
  if (h[threadIdx.x])
    base[threadIdx.x] = atomicAdd(&bcursor[threadIdx.x], h[threadIdx.x]);
  __syncthreads();
  for (int e = c0 + (int)threadIdx.x; e < c1; e += 256) {
    int dst = ei[E + e];
    int src = ei[e];
    int b = dst >> BSHIFT;
    int r = atomicAdd(&cur[b], 1);
    pairs[base[b] + r] = ((unsigned)src << BSHIFT) | (unsigned)(dst & (BDSTS - 1));
  }
}

__global__ __launch_bounds__(256) void fine_kernel(
    const unsigned* __restrict__ pairs, const int* __restrict__ bstart,
    int* __restrict__ row_start, int* __restrict__ esrc, int N) {
  __shared__ int h[BDSTS], sc[BDSTS], cur[BDSTS];
  int t = threadIdx.x;
  int b = blockIdx.x;
  int d0 = b << BSHIFT;
  int beg = bstart[b], end = bstart[b + 1];
  h[t] = 0;
  __syncthreads();
  for (int i = beg + t; i < end; i += 256) atomicAdd(&h[pairs[i] & (BDSTS - 1)], 1);
  __syncthreads();
  int v = h[t];
  sc[t] = v;
  __syncthreads();
#pragma unroll
  for (int off = 1; off < BDSTS; off <<= 1) {
    int tmp = (t >= off) ? sc[t - off] : 0;
    __syncthreads();
    sc[t] += tmp;
    __syncthreads();
  }
  int excl = sc[t] - v;
  if (d0 + t < N) row_start[d0 + t] = beg + excl;
  cur[t] = excl;
  __syncthreads();
  for (int i = beg + t; i < end; i += 256) {
    unsigned p = pairs[i];
    int r = atomicAdd(&cur[p & (BDSTS - 1)], 1);
    esrc[beg + r] = (int)(p >> BSHIFT);
  }
}

// ---------------- W prep (fp16 transpose) + workspace zeroing ----------------

__global__ __launch_bounds__(256) void prep_w_kernel(
    const float* __restrict__ W1, const float* __restrict__ Wmu, const float* __restrict__ Wls,
    _Float16* __restrict__ Wt1, _Float16* __restrict__ Wt2,
    int* __restrict__ bcount, int* __restrict__ done, int NBUCK) {
  int idx = blockIdx.x * 256 + threadIdx.x;  // 16384 total
  int c = idx >> 7, k = idx & 127;
  Wt1[idx] = (_Float16)W1[k * 128 + c];
  float w2 = (c < 64) ? Wmu[k * 64 + c] : Wls[k * 64 + (c - 64)];
  Wt2[idx] = (_Float16)w2;
  if (blockIdx.x == 0) {
    if ((int)threadIdx.x <= NBUCK) bcount[threadIdx.x] = 0;
    if (threadIdx.x == 255) *done = 0;
  }
}

// ---------------- GEMM1 via MFMA, fused with bucket_hist + last-block scan ----------------

__global__ __launch_bounds__(256) void gemm1_hist(
    const float* __restrict__ X, const _Float16* __restrict__ Wt,
    const float* __restrict__ a_src, const float* __restrict__ a_dst,
    unsigned short* __restrict__ Hb, float* __restrict__ asrc, float* __restrict__ adst, int N,
    const int* __restrict__ ei, int* __restrict__ bcount, int E, int nGB, int nHB,
    int* __restrict__ bstart, int* __restrict__ bcursor, int* __restrict__ row_start,
    int* __restrict__ done, int NBUCK) {
  if ((int)blockIdx.x >= nGB) {
    __shared__ int h[256];
    __shared__ int lastFlag;
    h[threadIdx.x] = 0;
    __syncthreads();
    int hb = (int)blockIdx.x - nGB;
    int c0 = hb * 2048;
    int c1 = min(c0 + 2048, E);
    for (int e = c0 + (int)threadIdx.x; e < c1; e += 256)
      atomicAdd(&h[ei[E + e] >> BSHIFT], 1);
    __syncthreads();
    if (h[threadIdx.x]) atomicAdd(&bcount[threadIdx.x], h[threadIdx.x]);
    __syncthreads();  // all this block's device atomics drained before election
    if (threadIdx.x == 0) {
      __threadfence();
      lastFlag = (atomicAdd(done, 1) == nHB - 1) ? 1 : 0;
    }
    __syncthreads();
    if (lastFlag) {
      // exclusive scan of bcount (coherent atomic reads)
      int t = threadIdx.x;
      int v = (t < NBUCK) ? atomicAdd(&bcount[t], 0) : 0;
      h[t] = v;
      __syncthreads();
#pragma unroll
      for (int off = 1; off < 256; off <<= 1) {
        int tmp = (t >= off) ? h[t - off] : 0;
        __syncthreads();
        h[t] += tmp;
        __syncthreads();
      }
      if (t < NBUCK) {
        int excl = h[t] - v;
        bstart[t] = excl;
        bcursor[t] = excl;
      }
      if (t == 0) { bstart[NBUCK] = E; row_start[N] = E; }
    }
    return;
  }
  const int wid = threadIdx.x >> 6, lane = threadIdx.x & 63;
  const int r16 = ((int)blockIdx.x * 4 + wid) * 16;
  if (r16 >= N) return;
  const int cg = lane & 15;
  const int kq = (lane >> 4) * 8;
  const int rowClamp = min(r16 + cg, N - 1);

  f32x4 acc[8];
#pragma unroll
  for (int j = 0; j < 8; ++j) acc[j] = (f32x4){0.f, 0.f, 0.f, 0.f};

#pragma unroll
  for (int ks = 0; ks < 4; ++ks) {
    const int k0 = ks * 32;
    const float* xp = X + (size_t)rowClamp * 128 + k0 + kq;
    float4 xa = *(const float4*)xp;
    float4 xb = *(const float4*)(xp + 4);
    half8 a;
    a[0] = (_Float16)xa.x; a[1] = (_Float16)xa.y; a[2] = (_Float16)xa.z; a[3] = (_Float16)xa.w;
    a[4] = (_Float16)xb.x; a[5] = (_Float16)xb.y; a[6] = (_Float16)xb.z; a[7] = (_Float16)xb.w;
#pragma unroll
    for (int j = 0; j < 8; ++j) {
      half8 b = *(const half8*)(Wt + (size_t)(16 * j + cg) * 128 + k0 + kq);
      acc[j] = __builtin_amdgcn_mfma_f32_16x16x32_f16(a, b, acc[j], 0, 0, 0);
    }
  }

  float as_[8], ds_[8];
#pragma unroll
  for (int j = 0; j < 8; ++j) { as_[j] = a_src[16 * j + cg]; ds_[j] = a_dst[16 * j + cg]; }
  const int rg = (lane >> 4) * 4;
#pragma unroll
  for (int reg = 0; reg < 4; ++reg) {
    int row = r16 + rg + reg;
    bool ok = row < N;
    float ps = 0.f, pd = 0.f;
#pragma unroll
    for (int j = 0; j < 8; ++j) {
      float v = acc[j][reg];
      if (ok) Hb[(size_t)row * 128 + 16 * j + cg] = f2bf(v);
      ps = fmaf(v, as_[j], ps);
      pd = fmaf(v, ds_[j], pd);
    }
#pragma unroll
    for (int o = 1; o < 16; o <<= 1) { ps += __shfl_xor(ps, o); pd += __shfl_xor(pd, o); }
    if (ok && cg == 0) { asrc[row] = ps; adst[row] = pd; }
  }
}

__global__ __launch_bounds__(256) void gemm2_mfma(
    const _Float16* __restrict__ Xh, const _Float16* __restrict__ Wt,
    const float* __restrict__ a_src_mu, const float* __restrict__ a_dst_mu,
    const float* __restrict__ a_src_ls, const float* __restrict__ a_dst_ls,
    unsigned short* __restrict__ Hb, float* __restrict__ as2, float* __restrict__ ad2, int N) {
  const int wid = threadIdx.x >> 6, lane = threadIdx.x & 63;
  const int r16 = ((int)blockIdx.x * 4 + wid) * 16;
  if (r16 >= N) return;
  const int cg = lane & 15;
  const int kq = (lane >> 4) * 8;
  const int rowClamp = min(r16 + cg, N - 1);

  f32x4 acc[8];
#pragma unroll
  for (int j = 0; j < 8; ++j) acc[j] = (f32x4){0.f, 0.f, 0.f, 0.f};

#pragma unroll
  for (int ks = 0; ks < 4; ++ks) {
    const int k0 = ks * 32;
    half8 a = *(const half8*)(Xh + (size_t)rowClamp * 128 + k0 + kq);
#pragma unroll
    for (int j = 0; j < 8; ++j) {
      half8 b = *(const half8*)(Wt + (size_t)(16 * j + cg) * 128 + k0 + kq);
      acc[j] = __builtin_amdgcn_mfma_f32_16x16x32_f16(a, b, acc[j], 0, 0, 0);
    }
  }

  float asv[8], adv[8];
#pragma unroll
  for (int j = 0; j < 4; ++j) {
    asv[j] = a_src_mu[16 * j + cg]; adv[j] = a_dst_mu[16 * j + cg];
    asv[j + 4] = a_src_ls[16 * j + cg]; adv[j + 4] = a_dst_ls[16 * j + cg];
  }
  const int rg = (lane >> 4) * 4;
#pragma unroll
  for (int reg = 0; reg < 4; ++reg) {
    int row = r16 + rg + reg;
    bool ok = row < N;
    float psm = 0.f, pdm = 0.f, psl = 0.f, pdl = 0.f;
#pragma unroll
    for (int j = 0; j < 8; ++j) {
      float v = acc[j][reg];
      if (ok) Hb[(size_t)row * 128 + 16 * j + cg] = f2bf(v);
      if (j < 4) { psm = fmaf(v, asv[j], psm); pdm = fmaf(v, adv[j], pdm); }
      else       { psl = fmaf(v, asv[j], psl); pdl = fmaf(v, adv[j], pdl); }
    }
#pragma unroll
    for (int o = 1; o < 16; o <<= 1) {
      psm += __shfl_xor(psm, o); pdm += __shfl_xor(pdm, o);
      psl += __shfl_xor(psl, o); pdl += __shfl_xor(pdl, o);
    }
    if (ok && cg == 0) {
      as2[2 * row] = psm; ad2[2 * row] = pdm;
      as2[2 * row + 1] = psl; ad2[2 * row + 1] = pdl;
    }
  }
}

// ---------------- Aggregation layer 1: 16-lane groups, 16B gathers ----------------
// wave = 2 dsts (half = lane>>5); per half, 2 groups of 16 lanes process 2 edges
// concurrently; lane li owns channels li*8..+7 (uint4 = 8 bf16).

#define STEP1(J)                                                          \
  {                                                                       \
    int idx = (J) + grp;                                                  \
    int sA = __shfl(s, hbase + idx);                                      \
    float wA = __shfl(w, hbase + idx);                                    \
    uint4 hv = *(const uint4*)(Hb + (size_t)sA * 128 + li * 8);           \
    float2 q0 = bfp(hv.x), q1 = bfp(hv.y), q2 = bfp(hv.z), q3 = bfp(hv.w);\
    a0 = fmaf(wA, q0.x, a0); a1 = fmaf(wA, q0.y, a1);                     \
    a2 = fmaf(wA, q1.x, a2); a3 = fmaf(wA, q1.y, a3);                     \
    a4 = fmaf(wA, q2.x, a4); a5 = fmaf(wA, q2.y, a5);                     \
    a6 = fmaf(wA, q3.x, a6); a7 = fmaf(wA, q3.y, a7);                     \
  }

__global__ __launch_bounds__(256) void agg1_g16(
    const unsigned short* __restrict__ Hb, const float* __restrict__ asrc,
    const float* __restrict__ adst, const int* __restrict__ row_start,
    const int* __restrict__ esrc, const float* __restrict__ b,
    _Float16* __restrict__ hout, int N) {
  const int lane = threadIdx.x & 63;
  const int half = lane >> 5, sub = lane & 31;
  const int grp = (lane >> 4) & 1, li = lane & 15;
  const int g = (int)(blockIdx.x * 4 + (threadIdx.x >> 6));
  const int d = g * 2 + half;
  const bool dok = d < N;
  const int dc = dok ? d : N - 1;
  const float ad = adst[dc];
  const float wself = __expf(leaky02(asrc[dc] + ad));
  float a0 = 0.f, a1 = 0.f, a2 = 0.f, a3 = 0.f, a4 = 0.f, a5 = 0.f, a6 = 0.f, a7 = 0.f;
  if (grp == 0) {
    uint4 sv = *(const uint4*)(Hb + (size_t)dc * 128 + li * 8);
    float2 q0 = bfp(sv.x), q1 = bfp(sv.y), q2 = bfp(sv.z), q3 = bfp(sv.w);
    a0 = wself * q0.x; a1 = wself * q0.y; a2 = wself * q1.x; a3 = wself * q1.y;
    a4 = wself * q2.x; a5 = wself * q2.y; a6 = wself * q3.x; a7 = wself * q3.y;
  }
  float den = (sub == 0) ? wself : 0.f;
  const int beg = row_start[dc];
  const int n = dok ? (row_start[dc + 1] - beg) : 0;
  const int nmax = max(n, __shfl_xor(n, 32));
  const int hbase = half * 32;
  for (int c0 = 0; c0 < nmax; c0 += 32) {
    int j = c0 + sub;
    bool v = j < n;
    int s = v ? esrc[beg + j] : 0;
    float w = v ? __expf(leaky02(asrc[s] + ad)) : 0.f;
    den += w;
    int cnt = n - c0;
    cnt = min(max(cnt, 0), 32);
    int jj = 0;
    for (; jj + 8 <= cnt; jj += 8) { STEP1(jj) STEP1(jj + 2) STEP1(jj + 4) STEP1(jj + 6) }
    for (; jj < cnt; jj += 2) {
      int idx = jj + grp;
      int sA = __shfl(s, hbase + idx);
      float wA = __shfl(w, hbase + idx);
      if (idx < cnt) {
        uint4 hv = *(const uint4*)(Hb + (size_t)sA * 128 + li * 8);
        float2 q0 = bfp(hv.x), q1 = bfp(hv.y), q2 = bfp(hv.z), q3 = bfp(hv.w);
        a0 = fmaf(wA, q0.x, a0); a1 = fmaf(wA, q0.y, a1);
        a2 = fmaf(wA, q1.x, a2); a3 = fmaf(wA, q1.y, a3);
        a4 = fmaf(wA, q2.x, a4); a5 = fmaf(wA, q2.y, a5);
        a6 = fmaf(wA, q3.x, a6); a7 = fmaf(wA, q3.y, a7);
      }
    }
  }
  // merge the two groups of each half, then reduce den across the half
  a0 += __shfl_xor(a0, 16); a1 += __shfl_xor(a1, 16);
  a2 += __shfl_xor(a2, 16); a3 += __shfl_xor(a3, 16);
  a4 += __shfl_xor(a4, 16); a5 += __shfl_xor(a5, 16);
  a6 += __shfl_xor(a6, 16); a7 += __shfl_xor(a7, 16);
#pragma unroll
  for (int o = 16; o > 0; o >>= 1) den += __shfl_xor(den, o);
  if (dok && grp == 0) {
    float inv = 1.0f / den;
    float4 b0 = *(const float4*)(b + li * 8);
    float4 b1 = *(const float4*)(b + li * 8 + 4);
    _Float16 o8[8];
    o8[0] = (_Float16)fmaxf(fmaf(a0, inv, b0.x), 0.f);
    o8[1] = (_Float16)fmaxf(fmaf(a1, inv, b0.y), 0.f);
    o8[2] = (_Float16)fmaxf(fmaf(a2, inv, b0.z), 0.f);
    o8[3] = (_Float16)fmaxf(fmaf(a3, inv, b0.w), 0.f);
    o8[4] = (_Float16)fmaxf(fmaf(a4, inv, b1.x), 0.f);
    o8[5] = (_Float16)fmaxf(fmaf(a5, inv, b1.y), 0.f);
    o8[6] = (_Float16)fmaxf(fmaf(a6, inv, b1.z), 0.f);
    o8[7] = (_Float16)fmaxf(fmaf(a7, inv, b1.w), 0.f);
    *(uint4*)(hout + (size_t)d * 128 + li * 8) = *(uint4*)o8;
  }
}

// ---------------- Aggregation layers 2+3 fused: 16-lane groups ----------------
// lane li<8 -> mu channels li*8..+7; li>=8 -> ls channels (li-8)*8..+7.

#define STEP2(J)                                                          \
  {                                                                       \
    int idx = (J) + grp;                                                  \
    int sA = __shfl(s, hbase + idx);                                      \
    float wmA = __shfl(wm, hbase + idx);                                  \
    float wlA = __shfl(wl, hbase + idx);                                  \
    float wA = isMu ? wmA : wlA;                                          \
    uint4 hv = *(const uint4*)(Hb + (size_t)sA * 128 + li * 8);           \
    float2 q0 = bfp(hv.x), q1 = bfp(hv.y), q2 = bfp(hv.z), q3 = bfp(hv.w);\
    a0 = fmaf(wA, q0.x, a0); a1 = fmaf(wA, q0.y, a1);                     \
    a2 = fmaf(wA, q1.x, a2); a3 = fmaf(wA, q1.y, a3);                     \
    a4 = fmaf(wA, q2.x, a4); a5 = fmaf(wA, q2.y, a5);                     \
    a6 = fmaf(wA, q3.x, a6); a7 = fmaf(wA, q3.y, a7);                     \
  }

__global__ __launch_bounds__(256) void agg2_g16(
    const unsigned short* __restrict__ Hb,
    const float2* __restrict__ as2, const float2* __restrict__ ad2,
    const int* __restrict__ row_start, const int* __restrict__ esrc,
    const float* __restrict__ b_mu, const float* __restrict__ b_ls,
    float* __restrict__ out_mu, float* __restrict__ out_ls, int N) {
  const int lane = threadIdx.x & 63;
  const int half = lane >> 5, sub = lane & 31;
  const int grp = (lane >> 4) & 1, li = lane & 15;
  const bool isMu = li < 8;
  const int g = (int)(blockIdx.x * 4 + (threadIdx.x >> 6));
  const int d = g * 2 + half;
  const bool dok = d < N;
  const int dc = dok ? d : N - 1;
  const float2 adv = ad2[dc];
  const float2 asv = as2[dc];
  const float wself_m = __expf(leaky02(asv.x + adv.x));
  const float wself_l = __expf(leaky02(asv.y + adv.y));
  float a0 = 0.f, a1 = 0.f, a2 = 0.f, a3 = 0.f, a4 = 0.f, a5 = 0.f, a6 = 0.f, a7 = 0.f;
  if (grp == 0) {
    const float wself = isMu ? wself_m : wself_l;
    uint4 sv = *(const uint4*)(Hb + (size_t)dc * 128 + li * 8);
    float2 q0 = bfp(sv.x), q1 = bfp(sv.y), q2 = bfp(sv.z), q3 = bfp(sv.w);
    a0 = wself * q0.x; a1 = wself * q0.y; a2 = wself * q1.x; a3 = wself * q1.y;
    a4 = wself * q2.x; a5 = wself * q2.y; a6 = wself * q3.x; a7 = wself * q3.y;
  }
  float den_m = (sub == 0) ? wself_m : 0.f;
  float den_l = (sub == 0) ? wself_l : 0.f;
  const int beg = row_start[dc];
  const int n = dok ? (row_start[dc + 1] - beg) : 0;
  const int nmax = max(n, __shfl_xor(n, 32));
  const int hbase = half * 32;
  for (int c0 = 0; c0 < nmax; c0 += 32) {
    int j = c0 + sub;
    bool v = j < n;
    int s = v ? esrc[beg + j] : 0;
    float wm = 0.f, wl = 0.f;
    if (v) {
      float2 av = as2[s];
      wm = __expf(leaky02(av.x + adv.x));
      wl = __expf(leaky02(av.y + adv.y));
    }
    den_m += wm;
    den_l += wl;
    int cnt = n - c0;
    cnt = min(max(cnt, 0), 32);
    int jj = 0;
    for (; jj + 8 <= cnt; jj += 8) { STEP2(jj) STEP2(jj + 2) STEP2(jj + 4) STEP2(jj + 6) }
    for (; jj < cnt; jj += 2) {
      int idx = jj + grp;
      int sA = __shfl(s, hbase + idx);
      float wmA = __shfl(wm, hbase + idx);
      float wlA = __shfl(wl, hbase + idx);
      float wA = isMu ? wmA : wlA;
      if (idx < cnt) {
        uint4 hv = *(const uint4*)(Hb + (size_t)sA * 128 + li * 8);
        float2 q0 = bfp(hv.x), q1 = bfp(hv.y), q2 = bfp(hv.z), q3 = bfp(hv.w);
        a0 = fmaf(wA, q0.x, a0); a1 = fmaf(wA, q0.y, a1);
        a2 = fmaf(wA, q1.x, a2); a3 = fmaf(wA, q1.y, a3);
        a4 = fmaf(wA, q2.x, a4); a5 = fmaf(wA, q2.y, a5);
        a6 = fmaf(wA, q3.x, a6); a7 = fmaf(wA, q3.y, a7);
      }
    }
  }
  a0 += __shfl_xor(a0, 16); a1 += __shfl_xor(a1, 16);
  a2 += __shfl_xor(a2, 16); a3 += __shfl_xor(a3, 16);
  a4 += __shfl_xor(a4, 16); a5 += __shfl_xor(a5, 16);
  a6 += __shfl_xor(a6, 16); a7 += __shfl_xor(a7, 16);
#pragma unroll
  for (int o = 16; o > 0; o >>= 1) {
    den_m += __shfl_xor(den_m, o);
    den_l += __shfl_xor(den_l, o);
  }
  if (dok && grp == 0) {
    float inv = isMu ? (1.0f / den_m) : (1.0f / den_l);
    const float* bp;
    float* op;
    if (isMu) { bp = b_mu + li * 8; op = out_mu + (size_t)d * 64 + li * 8; }
    else      { bp = b_ls + (li - 8) * 8; op = out_ls + (size_t)d * 64 + (li - 8) * 8; }
    float4 b0 = *(const float4*)bp;
    float4 b1 = *(const float4*)(bp + 4);
    float4 o0, o1;
    o0.x = fmaf(a0, inv, b0.x); o0.y = fmaf(a1, inv, b0.y);
    o0.z = fmaf(a2, inv, b0.z); o0.w = fmaf(a3, inv, b0.w);
    o1.x = fmaf(a4, inv, b1.x); o1.y = fmaf(a5, inv, b1.y);
    o1.z = fmaf(a6, inv, b1.z); o1.w = fmaf(a7, inv, b1.w);
    *(float4*)op = o0;
    *(float4*)(op + 4) = o1;
  }
}

// ---------------- launch ----------------

extern "C" void kernel_launch(void* const* d_in, const int* in_sizes, int n_in,
                              void* d_out, int out_size, void* d_ws, size_t ws_size,
                              hipStream_t stream) {
  const float* x = (const float*)d_in[0];
  const int* ei = (const int*)d_in[1];
  const float* W1 = (const float*)d_in[2];
  const float* a_src1 = (const float*)d_in[3];
  const float* a_dst1 = (const float*)d_in[4];
  const float* b1 = (const float*)d_in[5];
  const float* W_mu = (const float*)d_in[6];
  const float* a_src_mu = (const float*)d_in[7];
  const float* a_dst_mu = (const float*)d_in[8];
  const float* b_mu = (const float*)d_in[9];
  const float* W_ls = (const float*)d_in[10];
  const float* a_src_ls = (const float*)d_in[11];
  const float* a_dst_ls = (const float*)d_in[12];
  const float* b_ls = (const float*)d_in[13];

  const int N = in_sizes[0] / 128;  // 50000
  const int E = in_sizes[1] / 2;    // 800000
  const int NBUCK = (N + BDSTS - 1) >> BSHIFT;  // 196 (<=256)

  uint8_t* p = (uint8_t*)d_ws;
  auto carve = [&](size_t bytes) -> void* {
    void* q = (void*)p;
    p += (bytes + 255) & ~(size_t)255;
    return q;
  };
  int* bcount = (int*)carve((size_t)(NBUCK + 1) * 4);
  int* bstart = (int*)carve((size_t)(NBUCK + 1) * 4);
  int* bcursor = (int*)carve((size_t)NBUCK * 4);
  int* done = (int*)carve(4);
  int* row_start = (int*)carve((size_t)(N + 1) * 4);
  int* esrc = (int*)carve((size_t)E * 4);
  unsigned* pairs = (unsigned*)carve((size_t)E * 4);
  unsigned short* Hb1 = (unsigned short*)carve((size_t)N * 128 * 2);  // bf16; reused as Hb2
  _Float16* h1 = (_Float16*)carve((size_t)N * 128 * 2);               // fp16 gemm2 input
  _Float16* Wt1 = (_Float16*)carve((size_t)128 * 128 * 2);
  _Float16* Wt2 = (_Float16*)carve((size_t)128 * 128 * 2);
  float* as1 = (float*)carve((size_t)N * 4);
  float* ad1 = (float*)carve((size_t)N * 4);
  float* as2 = (float*)carve((size_t)N * 8);
  float* ad2 = (float*)carve((size_t)N * 8);

  unsigned short* Hb2 = Hb1;

  prep_w_kernel<<<64, 256, 0, stream>>>(W1, W_mu, W_ls, Wt1, Wt2, bcount, done, NBUCK);

  const int nGB = (N + 63) / 64;          // gemm1 blocks
  const int nHB = (E + 2047) / 2048;      // hist blocks
  gemm1_hist<<<nGB + nHB, 256, 0, stream>>>(x, Wt1, a_src1, a_dst1, Hb1, as1, ad1, N,
                                            ei, bcount, E, nGB, nHB,
                                            bstart, bcursor, row_start, done, NBUCK);
  pair_scatter_kernel<<<(E + CHUNK - 1) / CHUNK, 256, 0, stream>>>(ei, bcursor, pairs, E);
  fine_kernel<<<NBUCK, 256, 0, stream>>>(pairs, bstart, row_start, esrc, N);

  const int nwaves = (N + 1) / 2;
  const int nblk = (nwaves + 3) / 4;
  agg1_g16<<<nblk, 256, 0, stream>>>(Hb1, as1, ad1, row_start, esrc, b1, h1, N);
  gemm2_mfma<<<(N + 63) / 64, 256, 0, stream>>>(h1, Wt2, a_src_mu, a_dst_mu,
                                                a_src_ls, a_dst_ls, Hb2, as2, ad2, N);
  float* out_mu = (float*)d_out;
  float* out_ls = out_mu + (size_t)N * 64;
  agg2_g16<<<nblk, 256, 0, stream>>>(Hb2, (const float2*)as2, (const float2*)ad2,
                                     row_start, esrc, b_mu, b_ls, out_mu, out_ls, N);
}